// Round 1
// baseline (2604.682 us; speedup 1.0000x reference)
//
#include <hip/hip_runtime.h>
#include <math.h>

// Problem constants (fixed shapes from setup_inputs)
#define Dn   12
#define Hn   448
#define Wn   224
#define HWn  (Hn*Wn)        // 100352
#define DHWn (Dn*HWn)       // 1204224
#define Cn   10

// ---------- complex helpers ----------
__device__ __forceinline__ float2 cmul(float2 a, float2 b) {
    return make_float2(fmaf(a.x, b.x, -a.y * b.y), fmaf(a.x, b.y, a.y * b.x));
}
__device__ __forceinline__ float2 cfma(float2 a, float2 b, float2 acc) {
    // acc += a*b
    acc.x = fmaf(a.x, b.x, fmaf(-a.y, b.y, acc.x));
    acc.y = fmaf(a.x, b.y, fmaf(a.y, b.x, acc.y));
    return acc;
}
__host__ __device__ constexpr int brev5(int i) {
    return ((i & 1) << 4) | ((i & 2) << 2) | (i & 4) | ((i & 8) >> 2) | ((i & 16) >> 4);
}

__device__ __forceinline__ double waveReduce(double v) {
#pragma unroll
    for (int o = 32; o > 0; o >>= 1) v += __shfl_down(v, o, 64);
    return v;
}

// In-register 32-point DIF FFT. tw = LDS table of N-th roots e^{-2pi i j/N},
// BASE = N/32 (7 for N=224, 14 for N=448). sign=+1 forward, -1 inverse
// (conjugated twiddles). Output: x[i] = X[brev5(i)].
template<int BASE>
__device__ __forceinline__ void fft32(float2 (&x)[32], const float2* __restrict__ tw, float sign) {
#pragma unroll
    for (int s = 0; s < 5; ++s) {
        const int L = 32 >> s, half = L >> 1, step = BASE << s;
#pragma unroll
        for (int b0 = 0; b0 < 32; b0 += L) {
#pragma unroll
            for (int j = 0; j < half; ++j) {
                float2 a = x[b0 + j], c = x[b0 + j + half];
                x[b0 + j] = make_float2(a.x + c.x, a.y + c.y);
                float2 t = make_float2(a.x - c.x, a.y - c.y);
                float2 w = tw[j * step]; w.y *= sign;
                x[b0 + j + half] = cmul(t, w);
            }
        }
    }
}

// ---------- init kernels ----------
__global__ void k_init_misc(float2* __restrict__ tw224, float2* __restrict__ tw448,
                            double* __restrict__ S) {
    int t = threadIdx.x;  // 512 threads
    const double PI2 = 6.283185307179586476925287;
    if (t < 448) { double s, c; sincos(-(PI2 * t) / 448.0, &s, &c); tw448[t] = make_float2((float)c, (float)s); }
    if (t < 224) { double s, c; sincos(-(PI2 * t) / 224.0, &s, &c); tw224[t] = make_float2((float)c, (float)s); }
    if (t >= 448 && t < 480) S[t - 448] = 0.0;
}

// p' = fftshift(zerofilled_c + mu*z_c); r = p; b = 0; S[0] += |p|^2
__global__ void k_build_p(const float* __restrict__ z, const float* __restrict__ zf,
                          const float* __restrict__ miu,
                          float2* __restrict__ p, float2* __restrict__ r, float2* __restrict__ b,
                          double* __restrict__ S) {
    float mu = fabsf(miu[0]);
    double acc = 0.0;
    for (int e = blockIdx.x * blockDim.x + threadIdx.x; e < DHWn; e += gridDim.x * blockDim.x) {
        int d = e / HWn, rem = e - d * HWn;
        int h = rem / Wn, w = rem - h * Wn;
        int hs = h + Hn / 2; if (hs >= Hn) hs -= Hn;
        int ws = w + Wn / 2; if (ws >= Wn) ws -= Wn;
        int src = d * HWn + hs * Wn + ws;
        float pr = fmaf(mu, z[src], zf[src]);
        float pi = fmaf(mu, z[DHWn + src], zf[DHWn + src]);
        float2 v = make_float2(pr, pi);
        p[e] = v; r[e] = v; b[e] = make_float2(0.f, 0.f);
        acc += (double)pr * pr + (double)pi * pi;
    }
    acc = waveReduce(acc);
    if ((threadIdx.x & 63) == 0) atomicAdd(&S[0], acc);
}

__global__ void k_build_coil(const float* __restrict__ cr, const float* __restrict__ ci,
                             float2* __restrict__ coil) {
    for (int e = blockIdx.x * blockDim.x + threadIdx.x; e < Cn * HWn; e += gridDim.x * blockDim.x) {
        int c = e / HWn, rem = e - c * HWn;
        int h = rem / Wn, w = rem - h * Wn;
        int hs = h + Hn / 2; if (hs >= Hn) hs -= Hn;
        int ws = w + Wn / 2; if (ws >= Wn) ws -= Wn;
        int src = c * HWn + hs * Wn + ws;
        coil[e] = make_float2(cr[src], ci[src]);
    }
}

__global__ void k_build_mask(const int* __restrict__ mask, float* __restrict__ maskS) {
    for (int e = blockIdx.x * blockDim.x + threadIdx.x; e < HWn; e += gridDim.x * blockDim.x) {
        int h = e / Wn, w = e - h * Wn;
        int hs = h + Hn / 2; if (hs >= Hn) hs -= Hn;
        int ws = w + Wn / 2; if (ws >= Wn) ws -= Wn;
        maskS[e] = (float)mask[hs * Wn + ws] * (1.0f / (float)HWn);
    }
}

// ---------- row FFT (length 224 = 7*32) ----------
// INVERSE=0: read p[d], multiply by coil, row forward FFT, write Y1[cz][d] (natural layout)
// INVERSE=1: in-place on Y1[cz][d]: row inverse FFT, multiply conj(coil), write back
template<int INVERSE>
__global__ __launch_bounds__(256) void k_rowfft(const float2* __restrict__ src,
                                                const float2* __restrict__ coil,
                                                float2* __restrict__ Y1,
                                                const float2* __restrict__ twg,
                                                int chunkStart) {
    __shared__ float2 buf[32][225];  // 32 rows, pitch 225 (pad to break bank conflicts)
    __shared__ float2 tw[224];
    int tid = threadIdx.x;
    int h0 = blockIdx.x * 32;
    int d = blockIdx.y, cz = blockIdx.z;
    if (tid < 224) tw[tid] = twg[tid];
    size_t imgOff = ((size_t)cz * Dn + d) * (size_t)HWn;
    const float2* inrow = (INVERSE ? (const float2*)(Y1 + imgOff) : (src + (size_t)d * HWn))
                          + (size_t)h0 * Wn;
    const float2* cl = coil + (size_t)(chunkStart + cz) * HWn + (size_t)h0 * Wn;
    float2* outp = Y1 + imgOff + (size_t)h0 * Wn;
    __syncthreads();

    // load 32 rows (coalesced), forward: multiply by coil
    for (int i = tid; i < 32 * 224; i += 256) {
        int r = i / 224, w = i - r * 224;
        float2 v = inrow[r * Wn + w];
        if (!INVERSE) v = cmul(v, cl[r * Wn + w]);
        buf[r][w] = v;
    }
    __syncthreads();

    const float sign = INVERSE ? -1.f : 1.f;
    int rowA = tid / 7, n1A = tid - rowA * 7;  // 224 stage-1 tasks
    float2 x[32];
    if (tid < 224) {
#pragma unroll
        for (int n2 = 0; n2 < 32; ++n2) x[n2] = buf[rowA][n1A + 7 * n2];
        fft32<7>(x, tw, sign);
    }
    __syncthreads();
    if (tid < 224) {
#pragma unroll
        for (int i2 = 0; i2 < 32; ++i2) buf[rowA][n1A * 32 + brev5(i2)] = x[i2];
    }
    __syncthreads();

    // stage 2: X[k2+32*k1] = DFT7_{k1}( Y[n1][k2] * tw[k2]^n1 ), 1024 tasks
    float2 res[4][7];
#pragma unroll
    for (int t = 0; t < 4; ++t) {
        int task = tid + t * 256;
        int row = task >> 5, k2 = task & 31;
        float2 base = tw[k2]; base.y *= sign;
        float2 Z[7];
        float2 tc = make_float2(1.f, 0.f);
#pragma unroll
        for (int n1 = 0; n1 < 7; ++n1) {
            Z[n1] = cmul(buf[row][n1 * 32 + k2], tc);
            tc = cmul(tc, base);
        }
#pragma unroll
        for (int k1 = 0; k1 < 7; ++k1) {
            float2 s = Z[0];
#pragma unroll
            for (int n1 = 1; n1 < 7; ++n1) {
                float2 wv = tw[((n1 * k1) % 7) * 32]; wv.y *= sign;
                s = cfma(Z[n1], wv, s);
            }
            res[t][k1] = s;
        }
    }
    __syncthreads();
#pragma unroll
    for (int t = 0; t < 4; ++t) {
        int task = tid + t * 256;
        int row = task >> 5, k2 = task & 31;
#pragma unroll
        for (int k1 = 0; k1 < 7; ++k1) buf[row][k2 + 32 * k1] = res[t][k1];
    }
    __syncthreads();

    // store (coalesced); inverse: multiply conj(coil)
    for (int i = tid; i < 32 * 224; i += 256) {
        int r = i / 224, w = i - r * 224;
        float2 v = buf[r][w];
        if (INVERSE) {
            float2 c = cl[r * Wn + w];
            v = make_float2(fmaf(v.x, c.x, v.y * c.y), fmaf(v.y, c.x, -v.x * c.y));
        }
        outp[r * Wn + w] = v;
    }
}

// ---------- column FFT (length 448 = 14*32) + mask + column IFFT, fused, in-place ----------
__global__ __launch_bounds__(256) void k_colfft(float2* __restrict__ Y1,
                                                const float* __restrict__ maskS,
                                                const float2* __restrict__ twg) {
    __shared__ float2 buf[16][449];  // 16 columns, pitch 449
    __shared__ float2 tw[448];
    int tid = threadIdx.x;
    int w0 = blockIdx.x * 16;
    int d = blockIdx.y, cz = blockIdx.z;
    for (int i = tid; i < 448; i += 256) tw[i] = twg[i];
    float2* img = Y1 + ((size_t)cz * Dn + d) * (size_t)HWn;
    __syncthreads();

    // load 16 columns; lanes walk w fastest -> 128B chunks per h
    for (int i = tid; i < 16 * 448; i += 256) {
        int col = i & 15, h = i >> 4;
        buf[col][h] = img[(size_t)h * Wn + w0 + col];
    }
    __syncthreads();

    int colA = tid / 14, n1A = tid - colA * 14;  // 224 stage-1 tasks
    float2 x[32];
    for (int pass = 0; pass < 2; ++pass) {   // pass0 = forward FFT + mask, pass1 = inverse FFT
        float sign = pass ? -1.f : 1.f;
        if (tid < 224) {
#pragma unroll
            for (int n2 = 0; n2 < 32; ++n2) x[n2] = buf[colA][n1A + 14 * n2];
            fft32<14>(x, tw, sign);
        }
        __syncthreads();
        if (tid < 224) {
#pragma unroll
            for (int i2 = 0; i2 < 32; ++i2) buf[colA][n1A * 32 + brev5(i2)] = x[i2];
        }
        __syncthreads();

        float2 res[2][14];
#pragma unroll
        for (int t = 0; t < 2; ++t) {
            int task = tid + t * 256;
            int col = task >> 5, k2 = task & 31;
            float2 base = tw[k2]; base.y *= sign;
            float2 Z[14];
            float2 tc = make_float2(1.f, 0.f);
#pragma unroll
            for (int n1 = 0; n1 < 14; ++n1) {
                Z[n1] = cmul(buf[col][n1 * 32 + k2], tc);
                tc = cmul(tc, base);
            }
#pragma unroll
            for (int k1 = 0; k1 < 14; ++k1) {
                float2 s = Z[0];
#pragma unroll
                for (int n1 = 1; n1 < 14; ++n1) {
                    float2 wv = tw[((n1 * k1) % 14) * 32]; wv.y *= sign;
                    s = cfma(Z[n1], wv, s);
                }
                if (pass == 0) {
                    int h = k2 + 32 * k1;
                    float m = maskS[h * Wn + w0 + col];  // mask/(H*W)
                    s.x *= m; s.y *= m;
                }
                res[t][k1] = s;
            }
        }
        __syncthreads();
#pragma unroll
        for (int t = 0; t < 2; ++t) {
            int task = tid + t * 256;
            int col = task >> 5, k2 = task & 31;
#pragma unroll
            for (int k1 = 0; k1 < 14; ++k1) buf[col][k2 + 32 * k1] = res[t][k1];
        }
        __syncthreads();
    }

    for (int i = tid; i < 16 * 448; i += 256) {
        int col = i & 15, h = i >> 4;
        img[(size_t)h * Wn + w0 + col] = buf[col][h];
    }
}

// ---------- combine: q = mu*p + sum_c Y1[c]; on last chunk also qp = sum q*conj(p) ----------
__global__ void k_combine(const float2* __restrict__ Y1, const float2* __restrict__ p,
                          float2* __restrict__ q, const float* __restrict__ miu,
                          double* __restrict__ S, int cc, int first, int last, int it) {
    float mu = fabsf(miu[0]);
    double ar = 0.0, ai = 0.0;
    for (int e = blockIdx.x * blockDim.x + threadIdx.x; e < DHWn; e += gridDim.x * blockDim.x) {
        float2 pv = make_float2(0.f, 0.f);
        float2 s;
        if (first) { pv = p[e]; s = make_float2(mu * pv.x, mu * pv.y); }
        else s = q[e];
        for (int cz = 0; cz < cc; ++cz) {
            float2 y = Y1[(size_t)cz * DHWn + e];
            s.x += y.x; s.y += y.y;
        }
        q[e] = s;
        if (last) {
            if (!first) pv = p[e];
            ar += (double)(s.x * pv.x + s.y * pv.y);   // Re(q*conj(p))
            ai += (double)(s.y * pv.x - s.x * pv.y);   // Im(q*conj(p))
        }
    }
    if (last) {
        ar = waveReduce(ar);
        ai = waveReduce(ai);
        if ((threadIdx.x & 63) == 0) {
            atomicAdd(&S[8 + it], ar);
            atomicAdd(&S[16 + it], ai);
        }
    }
}

// ---------- CG scalar updates ----------
// alpha = rr/qp (complex); b += alpha*p; r -= alpha*q; S[it+1] += |r|^2
__global__ void k_update_br(const double* __restrict__ Sin, double* __restrict__ S, int it,
                            const float2* __restrict__ p, const float2* __restrict__ q,
                            float2* __restrict__ b, float2* __restrict__ r) {
    double rr = Sin[it], qr = Sin[8 + it], qi = Sin[16 + it];
    double den = qr * qr + qi * qi;
    float arf = (float)(rr * qr / den);
    float aif = (float)(-rr * qi / den);
    double acc = 0.0;
    for (int e = blockIdx.x * blockDim.x + threadIdx.x; e < DHWn; e += gridDim.x * blockDim.x) {
        float2 pv = p[e], qv = q[e], bv = b[e], rv = r[e];
        bv.x += arf * pv.x - aif * pv.y;
        bv.y += arf * pv.y + aif * pv.x;
        b[e] = bv;
        rv.x -= arf * qv.x - aif * qv.y;
        rv.y -= arf * qv.y + aif * qv.x;
        r[e] = rv;
        acc += (double)rv.x * rv.x + (double)rv.y * rv.y;
    }
    acc = waveReduce(acc);
    if ((threadIdx.x & 63) == 0) atomicAdd(&S[it + 1], acc);
}

// beta = rr_next/rr; p = r + beta*p
__global__ void k_update_p(const double* __restrict__ S, int it,
                           const float2* __restrict__ r, float2* __restrict__ p) {
    float beta = (float)(S[it + 1] / S[it]);
    for (int e = blockIdx.x * blockDim.x + threadIdx.x; e < DHWn; e += gridDim.x * blockDim.x) {
        float2 rv = r[e], pv = p[e];
        p[e] = make_float2(fmaf(beta, pv.x, rv.x), fmaf(beta, pv.y, rv.y));
    }
}

// ---------- final unshift + split real/imag ----------
__global__ void k_output(const float2* __restrict__ b, float* __restrict__ out) {
    for (int e = blockIdx.x * blockDim.x + threadIdx.x; e < DHWn; e += gridDim.x * blockDim.x) {
        int d = e / HWn, rem = e - d * HWn;
        int h = rem / Wn, w = rem - h * Wn;
        int hs = h + Hn / 2; if (hs >= Hn) hs -= Hn;
        int ws = w + Wn / 2; if (ws >= Wn) ws -= Wn;
        float2 v = b[d * HWn + hs * Wn + ws];
        out[e] = v.x;
        out[DHWn + e] = v.y;
    }
}

extern "C" void kernel_launch(void* const* d_in, const int* in_sizes, int n_in,
                              void* d_out, int out_size, void* d_ws, size_t ws_size,
                              hipStream_t stream) {
    const float* z      = (const float*)d_in[0];
    const float* zf     = (const float*)d_in[1];
    const float* coil_r = (const float*)d_in[2];
    const float* coil_i = (const float*)d_in[3];
    const int*   maskp  = (const int*)d_in[4];
    const float* miu    = (const float*)d_in[5];
    float* out = (float*)d_out;

    char* w = (char*)d_ws;
    size_t off = 0;
    auto carve = [&](size_t bytes) -> void* {
        void* ptr = w + off;
        off += (bytes + 511) & ~(size_t)511;
        return ptr;
    };
    float2* P     = (float2*)carve((size_t)DHWn * 8);
    float2* R     = (float2*)carve((size_t)DHWn * 8);
    float2* Bv    = (float2*)carve((size_t)DHWn * 8);
    float2* Q     = (float2*)carve((size_t)DHWn * 8);
    float2* COIL  = (float2*)carve((size_t)Cn * HWn * 8);
    float*  MASKS = (float*)carve((size_t)HWn * 4);
    float2* TW224 = (float2*)carve(224 * 8);
    float2* TW448 = (float2*)carve(448 * 8);
    double* S     = (double*)carve(64 * 8);

    // coil-chunk size: largest of {10,5,2,1} whose Y1 staging fits in remaining ws
    size_t imgSet = (size_t)DHWn * 8;  // one coil-slot of D slices
    int cc = 1;
    {
        const int opts[4] = {10, 5, 2, 1};
        for (int i = 0; i < 4; ++i) {
            if (off + (size_t)opts[i] * imgSet <= ws_size) { cc = opts[i]; break; }
        }
    }
    float2* Y1 = (float2*)carve((size_t)cc * imgSet);
    int nch = Cn / cc;

    k_init_misc<<<1, 512, 0, stream>>>(TW224, TW448, S);
    k_build_p<<<1024, 256, 0, stream>>>(z, zf, miu, P, R, Bv, S);
    k_build_coil<<<1024, 256, 0, stream>>>(coil_r, coil_i, COIL);
    k_build_mask<<<512, 256, 0, stream>>>(maskp, MASKS);

    for (int it = 0; it < 5; ++it) {
        for (int ch = 0; ch < nch; ++ch) {
            int cs = ch * cc;
            dim3 g(14, Dn, cc);
            k_rowfft<0><<<g, 256, 0, stream>>>(P, COIL, Y1, TW224, cs);
            k_colfft<<<g, 256, 0, stream>>>(Y1, MASKS, TW448);
            k_rowfft<1><<<g, 256, 0, stream>>>(P, COIL, Y1, TW224, cs);
            k_combine<<<1024, 256, 0, stream>>>(Y1, P, Q, miu, S, cc,
                                                ch == 0 ? 1 : 0, ch == nch - 1 ? 1 : 0, it);
        }
        k_update_br<<<1024, 256, 0, stream>>>(S, S, it, P, Q, Bv, R);
        if (it < 4) k_update_p<<<1024, 256, 0, stream>>>(S, it, R, P);
    }
    k_output<<<1024, 256, 0, stream>>>(Bv, out);
}

// Round 2
// 2236.082 us; speedup vs baseline: 1.1648x; 1.1648x over previous
//
#include <hip/hip_runtime.h>
#include <math.h>

// Problem constants (fixed shapes from setup_inputs)
#define Dn   12
#define Hn   448
#define Wn   224
#define HWn  (Hn*Wn)        // 100352
#define DHWn (Dn*HWn)       // 1204224
#define Cn   10

// Small twiddle table layout (101 float2 in global, copied to LDS per block):
// [0..15]  w32^j   (j=0..15)
// [16..29] w14^j   (j=0..13)
// [30..36] w7^j    (j=0..6)
// [37..68] w448^j  (j=0..31)
// [69..100] w224^j (j=0..31)
#define TW_W32   0
#define TW_W14   16
#define TW_W7    30
#define TW_B448  37
#define TW_B224  69
#define TW_N     101

// ---------- complex helpers ----------
__device__ __forceinline__ float2 cmul(float2 a, float2 b) {
    return make_float2(fmaf(a.x, b.x, -a.y * b.y), fmaf(a.x, b.y, a.y * b.x));
}
__device__ __forceinline__ float2 cfma(float2 a, float2 b, float2 acc) {
    acc.x = fmaf(a.x, b.x, fmaf(-a.y, b.y, acc.x));
    acc.y = fmaf(a.x, b.y, fmaf(a.y, b.x, acc.y));
    return acc;
}
__host__ __device__ constexpr int brev5(int i) {
    return ((i & 1) << 4) | ((i & 2) << 2) | (i & 4) | ((i & 8) >> 2) | ((i & 16) >> 4);
}

__device__ __forceinline__ double waveReduce(double v) {
#pragma unroll
    for (int o = 32; o > 0; o >>= 1) v += __shfl_down(v, o, 64);
    return v;
}

// In-register 32-point DIF FFT using LDS w32 table (broadcast reads).
// sign=+1 forward, -1 inverse. Output: x[i] = X[brev5(i)].
__device__ __forceinline__ void fft32(float2 (&x)[32], const float2* __restrict__ w32, float sign) {
#pragma unroll
    for (int s = 0; s < 5; ++s) {
        const int L = 32 >> s, half = L >> 1;
#pragma unroll
        for (int b0 = 0; b0 < 32; b0 += L) {
#pragma unroll
            for (int j = 0; j < half; ++j) {
                float2 a = x[b0 + j], c = x[b0 + j + half];
                x[b0 + j] = make_float2(a.x + c.x, a.y + c.y);
                float2 t = make_float2(a.x - c.x, a.y - c.y);
                float2 w = w32[j << s]; w.y *= sign;
                x[b0 + j + half] = cmul(t, w);
            }
        }
    }
}

// ---------- init kernels ----------
__global__ void k_init_misc(float2* __restrict__ tws, double* __restrict__ S) {
    int t = threadIdx.x;  // 128 threads
    const double PI2 = 6.283185307179586476925287;
    if (t < 16)            { double s, c; sincos(-(PI2 * t) / 32.0,  &s, &c); tws[TW_W32 + t]  = make_float2((float)c, (float)s); }
    if (t >= 16 && t < 30) { int j = t - 16; double s, c; sincos(-(PI2 * j) / 14.0, &s, &c); tws[TW_W14 + j] = make_float2((float)c, (float)s); }
    if (t >= 30 && t < 37) { int j = t - 30; double s, c; sincos(-(PI2 * j) / 7.0,  &s, &c); tws[TW_W7 + j]  = make_float2((float)c, (float)s); }
    if (t >= 37 && t < 69) { int j = t - 37; double s, c; sincos(-(PI2 * j) / 448.0, &s, &c); tws[TW_B448 + j] = make_float2((float)c, (float)s); }
    if (t >= 69 && t < 101){ int j = t - 69; double s, c; sincos(-(PI2 * j) / 224.0, &s, &c); tws[TW_B224 + j] = make_float2((float)c, (float)s); }
    if (t >= 101 && t < 128) S[t - 101] = 0.0;
    if (t < 27) S[t + 27] = 0.0;
}

// p' = fftshift(zerofilled_c + mu*z_c); r = p; b = 0; S[0] += |p|^2
__global__ void k_build_p(const float* __restrict__ z, const float* __restrict__ zf,
                          const float* __restrict__ miu,
                          float2* __restrict__ p, float2* __restrict__ r, float2* __restrict__ b,
                          double* __restrict__ S) {
    float mu = fabsf(miu[0]);
    double acc = 0.0;
    for (int e = blockIdx.x * blockDim.x + threadIdx.x; e < DHWn; e += gridDim.x * blockDim.x) {
        int d = e / HWn, rem = e - d * HWn;
        int h = rem / Wn, w = rem - h * Wn;
        int hs = h + Hn / 2; if (hs >= Hn) hs -= Hn;
        int ws = w + Wn / 2; if (ws >= Wn) ws -= Wn;
        int src = d * HWn + hs * Wn + ws;
        float pr = fmaf(mu, z[src], zf[src]);
        float pi = fmaf(mu, z[DHWn + src], zf[DHWn + src]);
        float2 v = make_float2(pr, pi);
        p[e] = v; r[e] = v; b[e] = make_float2(0.f, 0.f);
        acc += (double)pr * pr + (double)pi * pi;
    }
    acc = waveReduce(acc);
    if ((threadIdx.x & 63) == 0) atomicAdd(&S[0], acc);
}

__global__ void k_build_coil(const float* __restrict__ cr, const float* __restrict__ ci,
                             float2* __restrict__ coil) {
    for (int e = blockIdx.x * blockDim.x + threadIdx.x; e < Cn * HWn; e += gridDim.x * blockDim.x) {
        int c = e / HWn, rem = e - c * HWn;
        int h = rem / Wn, w = rem - h * Wn;
        int hs = h + Hn / 2; if (hs >= Hn) hs -= Hn;
        int ws = w + Wn / 2; if (ws >= Wn) ws -= Wn;
        int src = c * HWn + hs * Wn + ws;
        coil[e] = make_float2(cr[src], ci[src]);
    }
}

__global__ void k_build_mask(const int* __restrict__ mask, float* __restrict__ maskS) {
    for (int e = blockIdx.x * blockDim.x + threadIdx.x; e < HWn; e += gridDim.x * blockDim.x) {
        int h = e / Wn, w = e - h * Wn;
        int hs = h + Hn / 2; if (hs >= Hn) hs -= Hn;
        int ws = w + Wn / 2; if (ws >= Wn) ws -= Wn;
        maskS[e] = (float)mask[hs * Wn + ws] * (1.0f / (float)HWn);
    }
}

// ---------- row FFT (length 224 = 7*32), 8 rows/block, 64 threads (1 wave) ----------
// INVERSE=0: read p[d], multiply by coil, row forward FFT, write Y1[cz][d]
// INVERSE=1: in-place on Y1[cz][d]: row inverse FFT, multiply conj(coil)
#define RPITCH 230   // >= 33*6+31+1 = 230; 230%16=6 spreads banks
template<int INVERSE>
__global__ __launch_bounds__(64) void k_rowfft(const float2* __restrict__ src,
                                               const float2* __restrict__ coil,
                                               float2* __restrict__ Y1,
                                               const float2* __restrict__ twg,
                                               int chunkStart) {
    __shared__ float2 buf[8][RPITCH];
    __shared__ float2 tws[TW_N];
    int tid = threadIdx.x;
    int h0 = blockIdx.x * 8;
    int d = blockIdx.y, cz = blockIdx.z;
    for (int i = tid; i < TW_N; i += 64) tws[i] = twg[i];
    const float2* w32 = tws + TW_W32;
    const float2* w7  = tws + TW_W7;
    const float2* b224 = tws + TW_B224;
    size_t imgOff = ((size_t)cz * Dn + d) * (size_t)HWn;
    const float2* inrow = (INVERSE ? (const float2*)(Y1 + imgOff) : (src + (size_t)d * HWn))
                          + (size_t)h0 * Wn;
    const float2* cl = coil + (size_t)(chunkStart + cz) * HWn + (size_t)h0 * Wn;
    float2* outp = Y1 + imgOff + (size_t)h0 * Wn;
    __syncthreads();

    // load 8 rows (coalesced); forward: multiply by coil
    for (int i = tid; i < 8 * 224; i += 64) {
        int r = i / 224, w = i - r * 224;
        float2 v = inrow[r * Wn + w];
        if (!INVERSE) v = cmul(v, cl[r * Wn + w]);
        buf[r][w] = v;
    }
    __syncthreads();

    const float sign = INVERSE ? -1.f : 1.f;
    // stage 1: 56 tasks (8 rows x 7 n1), single wave -> loads precede stores in order
    {
        int rowA = tid & 7, n1A = tid >> 3;   // column-fast mapping
        float2 x[32];
        if (tid < 56) {
#pragma unroll
            for (int n2 = 0; n2 < 32; ++n2) x[n2] = buf[rowA][n1A + 7 * n2];
            fft32(x, w32, sign);
#pragma unroll
            for (int i2 = 0; i2 < 32; ++i2) buf[rowA][33 * n1A + brev5(i2)] = x[i2];
        }
    }
    __syncthreads();

    // stage 2: X[k2+32*k1] = DFT7_{k1}( Y[n1][k2] * b224[k2]^n1 ), 256 tasks / 64 thr
    float2 res[4][7];
#pragma unroll
    for (int t = 0; t < 4; ++t) {
        int task = tid + t * 64;
        int row = task >> 5, k2 = task & 31;
        float2 base = b224[k2]; base.y *= sign;
        float2 Z[7];
        float2 tc = make_float2(1.f, 0.f);
#pragma unroll
        for (int n1 = 0; n1 < 7; ++n1) {
            Z[n1] = cmul(buf[row][33 * n1 + k2], tc);
            tc = cmul(tc, base);
        }
#pragma unroll
        for (int k1 = 0; k1 < 7; ++k1) {
            float2 s = Z[0];
#pragma unroll
            for (int n1 = 1; n1 < 7; ++n1) {
                float2 wv = w7[(n1 * k1) % 7]; wv.y *= sign;
                s = cfma(Z[n1], wv, s);
            }
            res[t][k1] = s;
        }
    }
    __syncthreads();
#pragma unroll
    for (int t = 0; t < 4; ++t) {
        int task = tid + t * 64;
        int row = task >> 5, k2 = task & 31;
#pragma unroll
        for (int k1 = 0; k1 < 7; ++k1) buf[row][k2 + 32 * k1] = res[t][k1];
    }
    __syncthreads();

    // store (coalesced); inverse: multiply conj(coil)
    for (int i = tid; i < 8 * 224; i += 64) {
        int r = i / 224, w = i - r * 224;
        float2 v = buf[r][w];
        if (INVERSE) {
            float2 c = cl[r * Wn + w];
            v = make_float2(fmaf(v.x, c.x, v.y * c.y), fmaf(v.y, c.x, -v.x * c.y));
        }
        outp[r * Wn + w] = v;
    }
}

// ---------- column FFT (448 = 14*32) + mask + IFFT fused, 8 cols/block, 128 thr ----------
#define CPITCH 462   // >= 33*13+31+1 = 461; 462%16=14 spreads banks
__global__ __launch_bounds__(128) void k_colfft(float2* __restrict__ Y1,
                                                const float* __restrict__ maskS,
                                                const float2* __restrict__ twg) {
    __shared__ float2 buf[8][CPITCH];
    __shared__ float2 tws[TW_N];
    int tid = threadIdx.x;
    int w0 = blockIdx.x * 8;
    int d = blockIdx.y, cz = blockIdx.z;
    if (tid < TW_N) tws[tid] = twg[tid];
    const float2* w32 = tws + TW_W32;
    const float2* w14 = tws + TW_W14;
    const float2* w7  = tws + TW_W7;
    const float2* b448 = tws + TW_B448;
    float2* img = Y1 + ((size_t)cz * Dn + d) * (size_t)HWn;
    __syncthreads();

    // load 8 columns (64B segments per h)
    for (int i = tid; i < 8 * 448; i += 128) {
        int col = i & 7, h = i >> 3;
        buf[col][h] = img[(size_t)h * Wn + w0 + col];
    }
    __syncthreads();

    int colA = tid & 7, n1A = tid >> 3;   // column-fast mapping, 112 tasks
    float2 x[32];
    for (int pass = 0; pass < 2; ++pass) {   // pass0 = fwd FFT + mask, pass1 = inv FFT
        float sign = pass ? -1.f : 1.f;
        if (tid < 112) {
#pragma unroll
            for (int n2 = 0; n2 < 32; ++n2) x[n2] = buf[colA][n1A + 14 * n2];
            fft32(x, w32, sign);
        }
        __syncthreads();   // gathers (both waves) complete before scatter
        if (tid < 112) {
#pragma unroll
            for (int i2 = 0; i2 < 32; ++i2) buf[colA][33 * n1A + brev5(i2)] = x[i2];
        }
        __syncthreads();

        // stage 2: per k2-group, 14-point DFT via even/odd 2x DFT7. 256 tasks / 128 thr
        float2 res[2][14];
#pragma unroll
        for (int t = 0; t < 2; ++t) {
            int task = tid + t * 128;
            int col = task >> 5, k2 = task & 31;
            float2 base = b448[k2]; base.y *= sign;
            float2 Z[14];
            float2 tc = make_float2(1.f, 0.f);
#pragma unroll
            for (int n1 = 0; n1 < 14; ++n1) {
                Z[n1] = cmul(buf[col][33 * n1 + k2], tc);
                tc = cmul(tc, base);
            }
            // A[j] = sum_m Z[2m] w7^{mj}; B[j] = sum_m Z[2m+1] w7^{mj}
            float2 A[7], Bv[7];
#pragma unroll
            for (int j = 0; j < 7; ++j) {
                float2 sa = Z[0], sb = Z[1];
#pragma unroll
                for (int m = 1; m < 7; ++m) {
                    float2 wv = w7[(m * j) % 7]; wv.y *= sign;
                    sa = cfma(Z[2 * m], wv, sa);
                    sb = cfma(Z[2 * m + 1], wv, sb);
                }
                A[j] = sa; Bv[j] = sb;
            }
#pragma unroll
            for (int k1 = 0; k1 < 14; ++k1) {
                int j = k1 % 7;
                float2 wv = w14[k1]; wv.y *= sign;
                float2 s = cfma(Bv[j], wv, A[j]);
                if (pass == 0) {
                    int h = k2 + 32 * k1;
                    float m = maskS[h * Wn + w0 + col];  // mask/(H*W)
                    s.x *= m; s.y *= m;
                }
                res[t][k1] = s;
            }
        }
        __syncthreads();
#pragma unroll
        for (int t = 0; t < 2; ++t) {
            int task = tid + t * 128;
            int col = task >> 5, k2 = task & 31;
#pragma unroll
            for (int k1 = 0; k1 < 14; ++k1) buf[col][k2 + 32 * k1] = res[t][k1];
        }
        __syncthreads();
    }

    for (int i = tid; i < 8 * 448; i += 128) {
        int col = i & 7, h = i >> 3;
        img[(size_t)h * Wn + w0 + col] = buf[col][h];
    }
}

// ---------- combine: q = mu*p + sum_c Y1[c]; on last chunk also qp = sum q*conj(p) ----------
__global__ void k_combine(const float2* __restrict__ Y1, const float2* __restrict__ p,
                          float2* __restrict__ q, const float* __restrict__ miu,
                          double* __restrict__ S, int cc, int first, int last, int it) {
    float mu = fabsf(miu[0]);
    double ar = 0.0, ai = 0.0;
    for (int e = blockIdx.x * blockDim.x + threadIdx.x; e < DHWn; e += gridDim.x * blockDim.x) {
        float2 pv = make_float2(0.f, 0.f);
        float2 s;
        if (first) { pv = p[e]; s = make_float2(mu * pv.x, mu * pv.y); }
        else s = q[e];
        for (int cz = 0; cz < cc; ++cz) {
            float2 y = Y1[(size_t)cz * DHWn + e];
            s.x += y.x; s.y += y.y;
        }
        q[e] = s;
        if (last) {
            if (!first) pv = p[e];
            ar += (double)(s.x * pv.x + s.y * pv.y);   // Re(q*conj(p))
            ai += (double)(s.y * pv.x - s.x * pv.y);   // Im(q*conj(p))
        }
    }
    if (last) {
        ar = waveReduce(ar);
        ai = waveReduce(ai);
        if ((threadIdx.x & 63) == 0) {
            atomicAdd(&S[8 + it], ar);
            atomicAdd(&S[16 + it], ai);
        }
    }
}

// ---------- CG scalar updates ----------
__global__ void k_update_br(const double* __restrict__ Sin, double* __restrict__ S, int it,
                            const float2* __restrict__ p, const float2* __restrict__ q,
                            float2* __restrict__ b, float2* __restrict__ r) {
    double rr = Sin[it], qr = Sin[8 + it], qi = Sin[16 + it];
    double den = qr * qr + qi * qi;
    float arf = (float)(rr * qr / den);
    float aif = (float)(-rr * qi / den);
    double acc = 0.0;
    for (int e = blockIdx.x * blockDim.x + threadIdx.x; e < DHWn; e += gridDim.x * blockDim.x) {
        float2 pv = p[e], qv = q[e], bv = b[e], rv = r[e];
        bv.x += arf * pv.x - aif * pv.y;
        bv.y += arf * pv.y + aif * pv.x;
        b[e] = bv;
        rv.x -= arf * qv.x - aif * qv.y;
        rv.y -= arf * qv.y + aif * qv.x;
        r[e] = rv;
        acc += (double)rv.x * rv.x + (double)rv.y * rv.y;
    }
    acc = waveReduce(acc);
    if ((threadIdx.x & 63) == 0) atomicAdd(&S[it + 1], acc);
}

__global__ void k_update_p(const double* __restrict__ S, int it,
                           const float2* __restrict__ r, float2* __restrict__ p) {
    float beta = (float)(S[it + 1] / S[it]);
    for (int e = blockIdx.x * blockDim.x + threadIdx.x; e < DHWn; e += gridDim.x * blockDim.x) {
        float2 rv = r[e], pv = p[e];
        p[e] = make_float2(fmaf(beta, pv.x, rv.x), fmaf(beta, pv.y, rv.y));
    }
}

// ---------- final unshift + split real/imag ----------
__global__ void k_output(const float2* __restrict__ b, float* __restrict__ out) {
    for (int e = blockIdx.x * blockDim.x + threadIdx.x; e < DHWn; e += gridDim.x * blockDim.x) {
        int d = e / HWn, rem = e - d * HWn;
        int h = rem / Wn, w = rem - h * Wn;
        int hs = h + Hn / 2; if (hs >= Hn) hs -= Hn;
        int ws = w + Wn / 2; if (ws >= Wn) ws -= Wn;
        float2 v = b[d * HWn + hs * Wn + ws];
        out[e] = v.x;
        out[DHWn + e] = v.y;
    }
}

extern "C" void kernel_launch(void* const* d_in, const int* in_sizes, int n_in,
                              void* d_out, int out_size, void* d_ws, size_t ws_size,
                              hipStream_t stream) {
    const float* z      = (const float*)d_in[0];
    const float* zf     = (const float*)d_in[1];
    const float* coil_r = (const float*)d_in[2];
    const float* coil_i = (const float*)d_in[3];
    const int*   maskp  = (const int*)d_in[4];
    const float* miu    = (const float*)d_in[5];
    float* out = (float*)d_out;

    char* w = (char*)d_ws;
    size_t off = 0;
    auto carve = [&](size_t bytes) -> void* {
        void* ptr = w + off;
        off += (bytes + 511) & ~(size_t)511;
        return ptr;
    };
    float2* P     = (float2*)carve((size_t)DHWn * 8);
    float2* R     = (float2*)carve((size_t)DHWn * 8);
    float2* Bv    = (float2*)carve((size_t)DHWn * 8);
    float2* Q     = (float2*)carve((size_t)DHWn * 8);
    float2* COIL  = (float2*)carve((size_t)Cn * HWn * 8);
    float*  MASKS = (float*)carve((size_t)HWn * 4);
    float2* TWS   = (float2*)carve(TW_N * 8);
    double* S     = (double*)carve(64 * 8);

    size_t imgSet = (size_t)DHWn * 8;
    int cc = 1;
    {
        const int opts[4] = {10, 5, 2, 1};
        for (int i = 0; i < 4; ++i) {
            if (off + (size_t)opts[i] * imgSet <= ws_size) { cc = opts[i]; break; }
        }
    }
    float2* Y1 = (float2*)carve((size_t)cc * imgSet);
    int nch = Cn / cc;

    k_init_misc<<<1, 128, 0, stream>>>(TWS, S);
    k_build_p<<<1024, 256, 0, stream>>>(z, zf, miu, P, R, Bv, S);
    k_build_coil<<<1024, 256, 0, stream>>>(coil_r, coil_i, COIL);
    k_build_mask<<<512, 256, 0, stream>>>(maskp, MASKS);

    for (int it = 0; it < 5; ++it) {
        for (int ch = 0; ch < nch; ++ch) {
            int cs = ch * cc;
            dim3 gr(Hn / 8, Dn, cc);   // 56 x 12 x cc, 64-thread blocks
            dim3 gc(Wn / 8, Dn, cc);   // 28 x 12 x cc, 128-thread blocks
            k_rowfft<0><<<gr, 64, 0, stream>>>(P, COIL, Y1, TWS, cs);
            k_colfft<<<gc, 128, 0, stream>>>(Y1, MASKS, TWS);
            k_rowfft<1><<<gr, 64, 0, stream>>>(P, COIL, Y1, TWS, cs);
            k_combine<<<1024, 256, 0, stream>>>(Y1, P, Q, miu, S, cc,
                                                ch == 0 ? 1 : 0, ch == nch - 1 ? 1 : 0, it);
        }
        k_update_br<<<1024, 256, 0, stream>>>(S, S, it, P, Q, Bv, R);
        if (it < 4) k_update_p<<<1024, 256, 0, stream>>>(S, it, R, P);
    }
    k_output<<<1024, 256, 0, stream>>>(Bv, out);
}

// Round 3
// 2025.967 us; speedup vs baseline: 1.2856x; 1.1037x over previous
//
#include <hip/hip_runtime.h>
#include <math.h>

// Problem constants (fixed shapes from setup_inputs)
#define Dn   12
#define Hn   448
#define Wn   224
#define HWn  (Hn*Wn)        // 100352
#define DHWn (Dn*HWn)       // 1204224
#define Cn   10

// Twiddle table (101 float2 in global, copied to LDS per block):
#define TW_W32   0
#define TW_W14   16
#define TW_W7    30
#define TW_B448  37
#define TW_B224  69
#define TW_N     101

// ---------- complex helpers ----------
__device__ __forceinline__ float2 cmul(float2 a, float2 b) {
    return make_float2(fmaf(a.x, b.x, -a.y * b.y), fmaf(a.x, b.y, a.y * b.x));
}
__device__ __forceinline__ float2 cfma(float2 a, float2 b, float2 acc) {
    acc.x = fmaf(a.x, b.x, fmaf(-a.y, b.y, acc.x));
    acc.y = fmaf(a.x, b.y, fmaf(a.y, b.x, acc.y));
    return acc;
}
__host__ __device__ constexpr int brev5(int i) {
    return ((i & 1) << 4) | ((i & 2) << 2) | (i & 4) | ((i & 8) >> 2) | ((i & 16) >> 4);
}
// single-wave blocks: compiler fence; DS pipe is in-order per wave
__device__ __forceinline__ void wsync() { __builtin_amdgcn_wave_barrier(); }

__device__ __forceinline__ double waveReduce(double v) {
#pragma unroll
    for (int o = 32; o > 0; o >>= 1) v += __shfl_down(v, o, 64);
    return v;
}

// log-depth twiddle powers tp[j] = base^j (depth <= 4)
template<int NP>
__device__ __forceinline__ void twpow(float2 (&tp)[NP], float2 base) {
    tp[0] = make_float2(1.f, 0.f);
    tp[1] = base;
#pragma unroll
    for (int j = 2; j < NP; ++j) tp[j] = cmul(tp[j >> 1], tp[j - (j >> 1)]);
}

// In-register 32-point DIF FFT using LDS w32 table (broadcast reads).
__device__ __forceinline__ void fft32(float2 (&x)[32], const float2* __restrict__ w32, float sign) {
#pragma unroll
    for (int s = 0; s < 5; ++s) {
        const int L = 32 >> s, half = L >> 1;
#pragma unroll
        for (int b0 = 0; b0 < 32; b0 += L) {
#pragma unroll
            for (int j = 0; j < half; ++j) {
                float2 a = x[b0 + j], c = x[b0 + j + half];
                x[b0 + j] = make_float2(a.x + c.x, a.y + c.y);
                float2 t = make_float2(a.x - c.x, a.y - c.y);
                float2 w = w32[j << s]; w.y *= sign;
                x[b0 + j + half] = cmul(t, w);
            }
        }
    }
}

// ---------- init kernels ----------
__global__ void k_init_misc(float2* __restrict__ tws, double* __restrict__ S) {
    int t = threadIdx.x;  // 128 threads
    const double PI2 = 6.283185307179586476925287;
    if (t < 16)            { double s, c; sincos(-(PI2 * t) / 32.0,  &s, &c); tws[TW_W32 + t]  = make_float2((float)c, (float)s); }
    if (t >= 16 && t < 30) { int j = t - 16; double s, c; sincos(-(PI2 * j) / 14.0, &s, &c); tws[TW_W14 + j] = make_float2((float)c, (float)s); }
    if (t >= 30 && t < 37) { int j = t - 30; double s, c; sincos(-(PI2 * j) / 7.0,  &s, &c); tws[TW_W7 + j]  = make_float2((float)c, (float)s); }
    if (t >= 37 && t < 69) { int j = t - 37; double s, c; sincos(-(PI2 * j) / 448.0, &s, &c); tws[TW_B448 + j] = make_float2((float)c, (float)s); }
    if (t >= 69 && t < 101){ int j = t - 69; double s, c; sincos(-(PI2 * j) / 224.0, &s, &c); tws[TW_B224 + j] = make_float2((float)c, (float)s); }
    if (t >= 101 && t < 128) S[t - 101] = 0.0;
    if (t < 27) S[t + 27] = 0.0;
}

__global__ void k_build_p(const float* __restrict__ z, const float* __restrict__ zf,
                          const float* __restrict__ miu,
                          float2* __restrict__ p, float2* __restrict__ r, float2* __restrict__ b,
                          double* __restrict__ S) {
    float mu = fabsf(miu[0]);
    double acc = 0.0;
    for (int e = blockIdx.x * blockDim.x + threadIdx.x; e < DHWn; e += gridDim.x * blockDim.x) {
        int d = e / HWn, rem = e - d * HWn;
        int h = rem / Wn, w = rem - h * Wn;
        int hs = h + Hn / 2; if (hs >= Hn) hs -= Hn;
        int ws = w + Wn / 2; if (ws >= Wn) ws -= Wn;
        int src = d * HWn + hs * Wn + ws;
        float pr = fmaf(mu, z[src], zf[src]);
        float pi = fmaf(mu, z[DHWn + src], zf[DHWn + src]);
        float2 v = make_float2(pr, pi);
        p[e] = v; r[e] = v; b[e] = make_float2(0.f, 0.f);
        acc += (double)pr * pr + (double)pi * pi;
    }
    acc = waveReduce(acc);
    if ((threadIdx.x & 63) == 0) atomicAdd(&S[0], acc);
}

__global__ void k_build_coil(const float* __restrict__ cr, const float* __restrict__ ci,
                             float2* __restrict__ coil) {
    for (int e = blockIdx.x * blockDim.x + threadIdx.x; e < Cn * HWn; e += gridDim.x * blockDim.x) {
        int c = e / HWn, rem = e - c * HWn;
        int h = rem / Wn, w = rem - h * Wn;
        int hs = h + Hn / 2; if (hs >= Hn) hs -= Hn;
        int ws = w + Wn / 2; if (ws >= Wn) ws -= Wn;
        int src = c * HWn + hs * Wn + ws;
        coil[e] = make_float2(cr[src], ci[src]);
    }
}

// transposed, shifted, scaled mask: maskT[w*448 + h]
__global__ void k_build_mask(const int* __restrict__ mask, float* __restrict__ maskT) {
    for (int e = blockIdx.x * blockDim.x + threadIdx.x; e < HWn; e += gridDim.x * blockDim.x) {
        int w = e / Hn, h = e - w * Hn;
        int hs = h + Hn / 2; if (hs >= Hn) hs -= Hn;
        int ws = w + Wn / 2; if (ws >= Wn) ws -= Wn;
        maskT[e] = (float)mask[hs * Wn + ws] * (1.0f / (float)HWn);
    }
}

// ---------- row FFT (224 = 7*32), 8 rows/block, 64 threads, single wave, no barriers ----------
#define RPITCH 230
template<int INVERSE>
__global__ __launch_bounds__(64) void k_rowfft(const float2* __restrict__ src,
                                               const float2* __restrict__ coil,
                                               float2* __restrict__ Y1,
                                               const float2* __restrict__ twg,
                                               int chunkStart) {
    __shared__ float2 buf[8][RPITCH];
    __shared__ float2 tws[TW_N];
    int tid = threadIdx.x;
    int h0 = blockIdx.x * 8;
    int d = blockIdx.y, cz = blockIdx.z;
    for (int i = tid; i < TW_N; i += 64) tws[i] = twg[i];
    const float2* w32 = tws + TW_W32;
    const float2* w7  = tws + TW_W7;
    const float2* b224 = tws + TW_B224;
    size_t imgOff = ((size_t)cz * Dn + d) * (size_t)HWn;
    const float2* inrow = (INVERSE ? (const float2*)(Y1 + imgOff) : (src + (size_t)d * HWn))
                          + (size_t)h0 * Wn;
    const float2* cl = coil + (size_t)(chunkStart + cz) * HWn + (size_t)h0 * Wn;
    float2* outp = Y1 + imgOff + (size_t)h0 * Wn;
    wsync();

    for (int i = tid; i < 8 * 224; i += 64) {
        int r = i >> 5 >> 3, w = i & 223;          // i/224 would div; i: r = i/224
        r = i / 224; w = i - r * 224;
        float2 v = inrow[r * Wn + w];
        if (!INVERSE) v = cmul(v, cl[r * Wn + w]);
        buf[r][w] = v;
    }
    wsync();

    const float sign = INVERSE ? -1.f : 1.f;
    {   // stage 1: 56 tasks (8 rows x 7 n1)
        int rowA = tid & 7, n1A = tid >> 3;
        float2 x[32];
        if (tid < 56) {
#pragma unroll
            for (int n2 = 0; n2 < 32; ++n2) x[n2] = buf[rowA][n1A + 7 * n2];
            fft32(x, w32, sign);
        }
        wsync();
        if (tid < 56) {
#pragma unroll
            for (int i2 = 0; i2 < 32; ++i2) buf[rowA][33 * n1A + brev5(i2)] = x[i2];
        }
    }
    wsync();

    // stage 2: 256 tasks / 64 thr; twiddle powers via log-depth tree
    float2 res[4][7];
#pragma unroll
    for (int t = 0; t < 4; ++t) {
        int task = tid + t * 64;
        int row = task >> 5, k2 = task & 31;
        float2 base = b224[k2]; base.y *= sign;
        float2 tp[7]; twpow(tp, base);
        float2 Z[7];
#pragma unroll
        for (int n1 = 0; n1 < 7; ++n1) Z[n1] = cmul(buf[row][33 * n1 + k2], tp[n1]);
#pragma unroll
        for (int k1 = 0; k1 < 7; ++k1) {
            float2 s = Z[0];
#pragma unroll
            for (int n1 = 1; n1 < 7; ++n1) {
                float2 wv = w7[(n1 * k1) % 7]; wv.y *= sign;
                s = cfma(Z[n1], wv, s);
            }
            res[t][k1] = s;
        }
    }
    wsync();
#pragma unroll
    for (int t = 0; t < 4; ++t) {
        int task = tid + t * 64;
        int row = task >> 5, k2 = task & 31;
#pragma unroll
        for (int k1 = 0; k1 < 7; ++k1) buf[row][k2 + 32 * k1] = res[t][k1];
    }
    wsync();

    for (int i = tid; i < 8 * 224; i += 64) {
        int r = i / 224, w = i - r * 224;
        float2 v = buf[r][w];
        if (INVERSE) {
            float2 c = cl[r * Wn + w];
            v = make_float2(fmaf(v.x, c.x, v.y * c.y), fmaf(v.y, c.x, -v.x * c.y));
        }
        outp[r * Wn + w] = v;
    }
}

// ---------- column FFT (448 = 14*32) + mask + IFFT fused, 4 cols/block, 64 thr, 1 wave ----------
#define CPITCH 462
__global__ __launch_bounds__(64) void k_colfft(float2* __restrict__ Y1,
                                               const float* __restrict__ maskT,
                                               const float2* __restrict__ twg) {
    __shared__ float2 buf[4][CPITCH];
    __shared__ float2 tws[TW_N];
    int tid = threadIdx.x;
    int w0 = blockIdx.x * 4;
    int d = blockIdx.y, cz = blockIdx.z;
    for (int i = tid; i < TW_N; i += 64) tws[i] = twg[i];
    const float2* w32 = tws + TW_W32;
    const float2* w14 = tws + TW_W14;
    const float2* w7  = tws + TW_W7;
    const float2* b448 = tws + TW_B448;
    float2* img = Y1 + ((size_t)cz * Dn + d) * (size_t)HWn;
    wsync();

    for (int i = tid; i < 4 * 448; i += 64) {
        int col = i & 3, h = i >> 2;
        buf[col][h] = img[(size_t)h * Wn + w0 + col];
    }
    wsync();

    int colA = tid & 3, n1A = tid >> 2;   // 56 active stage-1 tasks
    float2 x[32];
    for (int pass = 0; pass < 2; ++pass) {
        float sign = pass ? -1.f : 1.f;
        if (n1A < 14) {
#pragma unroll
            for (int n2 = 0; n2 < 32; ++n2) x[n2] = buf[colA][n1A + 14 * n2];
            fft32(x, w32, sign);
        }
        wsync();
        if (n1A < 14) {
#pragma unroll
            for (int i2 = 0; i2 < 32; ++i2) buf[colA][33 * n1A + brev5(i2)] = x[i2];
        }
        wsync();

        // stage 2: 128 tasks / 64 thr, DFT14 via even/odd 2x DFT7
        float2 res[2][14];
#pragma unroll
        for (int t = 0; t < 2; ++t) {
            int task = tid + t * 64;
            int col = task >> 5, k2 = task & 31;
            float2 base = b448[k2]; base.y *= sign;
            float2 tp[14]; twpow(tp, base);
            float2 Z[14];
#pragma unroll
            for (int n1 = 0; n1 < 14; ++n1) Z[n1] = cmul(buf[col][33 * n1 + k2], tp[n1]);
            float2 A[7], Bv[7];
#pragma unroll
            for (int j = 0; j < 7; ++j) {
                float2 sa = Z[0], sb = Z[1];
#pragma unroll
                for (int m = 1; m < 7; ++m) {
                    float2 wv = w7[(m * j) % 7]; wv.y *= sign;
                    sa = cfma(Z[2 * m], wv, sa);
                    sb = cfma(Z[2 * m + 1], wv, sb);
                }
                A[j] = sa; Bv[j] = sb;
            }
            const float* mcol = maskT + (size_t)(w0 + col) * Hn;
#pragma unroll
            for (int k1 = 0; k1 < 14; ++k1) {
                int j = k1 % 7;
                float2 wv = w14[k1]; wv.y *= sign;
                float2 s = cfma(Bv[j], wv, A[j]);
                if (pass == 0) {
                    float m = mcol[k2 + 32 * k1];   // coalesced: lanes vary k2
                    s.x *= m; s.y *= m;
                }
                res[t][k1] = s;
            }
        }
        wsync();
#pragma unroll
        for (int t = 0; t < 2; ++t) {
            int task = tid + t * 64;
            int col = task >> 5, k2 = task & 31;
#pragma unroll
            for (int k1 = 0; k1 < 14; ++k1) buf[col][k2 + 32 * k1] = res[t][k1];
        }
        wsync();
    }

    for (int i = tid; i < 4 * 448; i += 64) {
        int col = i & 3, h = i >> 2;
        img[(size_t)h * Wn + w0 + col] = buf[col][h];
    }
}

// ---------- combine: q = mu*p + sum_c Y1[c]; last chunk: qp = sum q*conj(p) ----------
__global__ void k_combine(const float2* __restrict__ Y1, const float2* __restrict__ p,
                          float2* __restrict__ q, const float* __restrict__ miu,
                          double* __restrict__ S, int cc, int first, int last, int it) {
    float mu = fabsf(miu[0]);
    double ar = 0.0, ai = 0.0;
    for (int e = blockIdx.x * blockDim.x + threadIdx.x; e < DHWn; e += gridDim.x * blockDim.x) {
        float2 pv = make_float2(0.f, 0.f);
        float2 s;
        if (first) { pv = p[e]; s = make_float2(mu * pv.x, mu * pv.y); }
        else s = q[e];
        for (int cz = 0; cz < cc; ++cz) {
            float2 y = Y1[(size_t)cz * DHWn + e];
            s.x += y.x; s.y += y.y;
        }
        q[e] = s;
        if (last) {
            if (!first) pv = p[e];
            ar += (double)(s.x * pv.x + s.y * pv.y);
            ai += (double)(s.y * pv.x - s.x * pv.y);
        }
    }
    if (last) {
        ar = waveReduce(ar);
        ai = waveReduce(ai);
        if ((threadIdx.x & 63) == 0) {
            atomicAdd(&S[8 + it], ar);
            atomicAdd(&S[16 + it], ai);
        }
    }
}

__global__ void k_update_br(const double* __restrict__ Sin, double* __restrict__ S, int it,
                            const float2* __restrict__ p, const float2* __restrict__ q,
                            float2* __restrict__ b, float2* __restrict__ r) {
    double rr = Sin[it], qr = Sin[8 + it], qi = Sin[16 + it];
    double den = qr * qr + qi * qi;
    float arf = (float)(rr * qr / den);
    float aif = (float)(-rr * qi / den);
    double acc = 0.0;
    for (int e = blockIdx.x * blockDim.x + threadIdx.x; e < DHWn; e += gridDim.x * blockDim.x) {
        float2 pv = p[e], qv = q[e], bv = b[e], rv = r[e];
        bv.x += arf * pv.x - aif * pv.y;
        bv.y += arf * pv.y + aif * pv.x;
        b[e] = bv;
        rv.x -= arf * qv.x - aif * qv.y;
        rv.y -= arf * qv.y + aif * qv.x;
        r[e] = rv;
        acc += (double)rv.x * rv.x + (double)rv.y * rv.y;
    }
    acc = waveReduce(acc);
    if ((threadIdx.x & 63) == 0) atomicAdd(&S[it + 1], acc);
}

__global__ void k_update_p(const double* __restrict__ S, int it,
                           const float2* __restrict__ r, float2* __restrict__ p) {
    float beta = (float)(S[it + 1] / S[it]);
    for (int e = blockIdx.x * blockDim.x + threadIdx.x; e < DHWn; e += gridDim.x * blockDim.x) {
        float2 rv = r[e], pv = p[e];
        p[e] = make_float2(fmaf(beta, pv.x, rv.x), fmaf(beta, pv.y, rv.y));
    }
}

__global__ void k_output(const float2* __restrict__ b, float* __restrict__ out) {
    for (int e = blockIdx.x * blockDim.x + threadIdx.x; e < DHWn; e += gridDim.x * blockDim.x) {
        int d = e / HWn, rem = e - d * HWn;
        int h = rem / Wn, w = rem - h * Wn;
        int hs = h + Hn / 2; if (hs >= Hn) hs -= Hn;
        int ws = w + Wn / 2; if (ws >= Wn) ws -= Wn;
        float2 v = b[d * HWn + hs * Wn + ws];
        out[e] = v.x;
        out[DHWn + e] = v.y;
    }
}

extern "C" void kernel_launch(void* const* d_in, const int* in_sizes, int n_in,
                              void* d_out, int out_size, void* d_ws, size_t ws_size,
                              hipStream_t stream) {
    const float* z      = (const float*)d_in[0];
    const float* zf     = (const float*)d_in[1];
    const float* coil_r = (const float*)d_in[2];
    const float* coil_i = (const float*)d_in[3];
    const int*   maskp  = (const int*)d_in[4];
    const float* miu    = (const float*)d_in[5];
    float* out = (float*)d_out;

    char* w = (char*)d_ws;
    size_t off = 0;
    auto carve = [&](size_t bytes) -> void* {
        void* ptr = w + off;
        off += (bytes + 511) & ~(size_t)511;
        return ptr;
    };
    float2* P     = (float2*)carve((size_t)DHWn * 8);
    float2* R     = (float2*)carve((size_t)DHWn * 8);
    float2* Bv    = (float2*)carve((size_t)DHWn * 8);
    float2* Q     = (float2*)carve((size_t)DHWn * 8);
    float2* COIL  = (float2*)carve((size_t)Cn * HWn * 8);
    float*  MASKT = (float*)carve((size_t)HWn * 4);
    float2* TWS   = (float2*)carve(TW_N * 8);
    double* S     = (double*)carve(64 * 8);

    size_t imgSet = (size_t)DHWn * 8;
    int cc = 1;
    {
        const int opts[4] = {10, 5, 2, 1};
        for (int i = 0; i < 4; ++i) {
            if (off + (size_t)opts[i] * imgSet <= ws_size) { cc = opts[i]; break; }
        }
    }
    float2* Y1 = (float2*)carve((size_t)cc * imgSet);
    int nch = Cn / cc;

    k_init_misc<<<1, 128, 0, stream>>>(TWS, S);
    k_build_p<<<1024, 256, 0, stream>>>(z, zf, miu, P, R, Bv, S);
    k_build_coil<<<1024, 256, 0, stream>>>(coil_r, coil_i, COIL);
    k_build_mask<<<512, 256, 0, stream>>>(maskp, MASKT);

    for (int it = 0; it < 5; ++it) {
        for (int ch = 0; ch < nch; ++ch) {
            int cs = ch * cc;
            dim3 gr(Hn / 8, Dn, cc);   // 56 x 12 x cc, 64-thr single-wave blocks
            dim3 gc(Wn / 4, Dn, cc);   // 56 x 12 x cc, 64-thr single-wave blocks
            k_rowfft<0><<<gr, 64, 0, stream>>>(P, COIL, Y1, TWS, cs);
            k_colfft<<<gc, 64, 0, stream>>>(Y1, MASKT, TWS);
            k_rowfft<1><<<gr, 64, 0, stream>>>(P, COIL, Y1, TWS, cs);
            k_combine<<<1024, 256, 0, stream>>>(Y1, P, Q, miu, S, cc,
                                                ch == 0 ? 1 : 0, ch == nch - 1 ? 1 : 0, it);
        }
        k_update_br<<<1024, 256, 0, stream>>>(S, S, it, P, Q, Bv, R);
        if (it < 4) k_update_p<<<1024, 256, 0, stream>>>(S, it, R, P);
    }
    k_output<<<1024, 256, 0, stream>>>(Bv, out);
}

// Round 4
// 1882.059 us; speedup vs baseline: 1.3840x; 1.0765x over previous
//
#include <hip/hip_runtime.h>
#include <math.h>

// Problem constants (fixed shapes from setup_inputs)
#define Dn   12
#define Hn   448
#define Wn   224
#define HWn  (Hn*Wn)        // 100352
#define DHWn (Dn*HWn)       // 1204224
#define Cn   10

// Twiddle table (101 float2 in global, copied to LDS per block):
#define TW_W32   0
#define TW_W14   16
#define TW_W7    30
#define TW_B448  37
#define TW_B224  69
#define TW_N     101

// ---------- complex helpers ----------
__device__ __forceinline__ float2 cmul(float2 a, float2 b) {
    return make_float2(fmaf(a.x, b.x, -a.y * b.y), fmaf(a.x, b.y, a.y * b.x));
}
__device__ __forceinline__ float2 cfma(float2 a, float2 b, float2 acc) {
    acc.x = fmaf(a.x, b.x, fmaf(-a.y, b.y, acc.x));
    acc.y = fmaf(a.x, b.y, fmaf(a.y, b.x, acc.y));
    return acc;
}
__host__ __device__ constexpr int brev5(int i) {
    return ((i & 1) << 4) | ((i & 2) << 2) | (i & 4) | ((i & 8) >> 2) | ((i & 16) >> 4);
}
// single-wave blocks: compiler fence only; DS pipe is in-order per wave
__device__ __forceinline__ void wsync() { __builtin_amdgcn_wave_barrier(); }

__device__ __forceinline__ double waveReduce(double v) {
#pragma unroll
    for (int o = 32; o > 0; o >>= 1) v += __shfl_down(v, o, 64);
    return v;
}

// log-depth twiddle powers tp[j] = base^j (depth <= 4)
template<int NP>
__device__ __forceinline__ void twpow(float2 (&tp)[NP], float2 base) {
    tp[0] = make_float2(1.f, 0.f);
    tp[1] = base;
#pragma unroll
    for (int j = 2; j < NP; ++j) tp[j] = cmul(tp[j >> 1], tp[j - (j >> 1)]);
}

// In-register 32-point DIF FFT using LDS w32 table (broadcast reads).
__device__ __forceinline__ void fft32(float2 (&x)[32], const float2* __restrict__ w32, float sign) {
#pragma unroll
    for (int s = 0; s < 5; ++s) {
        const int L = 32 >> s, half = L >> 1;
#pragma unroll
        for (int b0 = 0; b0 < 32; b0 += L) {
#pragma unroll
            for (int j = 0; j < half; ++j) {
                float2 a = x[b0 + j], c = x[b0 + j + half];
                x[b0 + j] = make_float2(a.x + c.x, a.y + c.y);
                float2 t = make_float2(a.x - c.x, a.y - c.y);
                float2 w = w32[j << s]; w.y *= sign;
                x[b0 + j + half] = cmul(t, w);
            }
        }
    }
}

// ---------- init kernels ----------
__global__ void k_init_misc(float2* __restrict__ tws, double* __restrict__ S) {
    int t = threadIdx.x;  // 128 threads
    const double PI2 = 6.283185307179586476925287;
    if (t < 16)            { double s, c; sincos(-(PI2 * t) / 32.0,  &s, &c); tws[TW_W32 + t]  = make_float2((float)c, (float)s); }
    if (t >= 16 && t < 30) { int j = t - 16; double s, c; sincos(-(PI2 * j) / 14.0, &s, &c); tws[TW_W14 + j] = make_float2((float)c, (float)s); }
    if (t >= 30 && t < 37) { int j = t - 30; double s, c; sincos(-(PI2 * j) / 7.0,  &s, &c); tws[TW_W7 + j]  = make_float2((float)c, (float)s); }
    if (t >= 37 && t < 69) { int j = t - 37; double s, c; sincos(-(PI2 * j) / 448.0, &s, &c); tws[TW_B448 + j] = make_float2((float)c, (float)s); }
    if (t >= 69 && t < 101){ int j = t - 69; double s, c; sincos(-(PI2 * j) / 224.0, &s, &c); tws[TW_B224 + j] = make_float2((float)c, (float)s); }
    if (t >= 101 && t < 128) S[t - 101] = 0.0;
    if (t < 27) S[t + 27] = 0.0;
}

__global__ void k_build_p(const float* __restrict__ z, const float* __restrict__ zf,
                          const float* __restrict__ miu,
                          float2* __restrict__ p, float2* __restrict__ r, float2* __restrict__ b,
                          double* __restrict__ S) {
    float mu = fabsf(miu[0]);
    double acc = 0.0;
    for (int e = blockIdx.x * blockDim.x + threadIdx.x; e < DHWn; e += gridDim.x * blockDim.x) {
        int d = e / HWn, rem = e - d * HWn;
        int h = rem / Wn, w = rem - h * Wn;
        int hs = h + Hn / 2; if (hs >= Hn) hs -= Hn;
        int ws = w + Wn / 2; if (ws >= Wn) ws -= Wn;
        int src = d * HWn + hs * Wn + ws;
        float pr = fmaf(mu, z[src], zf[src]);
        float pi = fmaf(mu, z[DHWn + src], zf[DHWn + src]);
        float2 v = make_float2(pr, pi);
        p[e] = v; r[e] = v; b[e] = make_float2(0.f, 0.f);
        acc += (double)pr * pr + (double)pi * pi;
    }
    acc = waveReduce(acc);
    if ((threadIdx.x & 63) == 0) atomicAdd(&S[0], acc);
}

__global__ void k_build_coil(const float* __restrict__ cr, const float* __restrict__ ci,
                             float2* __restrict__ coil) {
    for (int e = blockIdx.x * blockDim.x + threadIdx.x; e < Cn * HWn; e += gridDim.x * blockDim.x) {
        int c = e / HWn, rem = e - c * HWn;
        int h = rem / Wn, w = rem - h * Wn;
        int hs = h + Hn / 2; if (hs >= Hn) hs -= Hn;
        int ws = w + Wn / 2; if (ws >= Wn) ws -= Wn;
        int src = c * HWn + hs * Wn + ws;
        coil[e] = make_float2(cr[src], ci[src]);
    }
}

// transposed, shifted, scaled mask: maskT[w*448 + h]
__global__ void k_build_mask(const int* __restrict__ mask, float* __restrict__ maskT) {
    for (int e = blockIdx.x * blockDim.x + threadIdx.x; e < HWn; e += gridDim.x * blockDim.x) {
        int w = e / Hn, h = e - w * Hn;
        int hs = h + Hn / 2; if (hs >= Hn) hs -= Hn;
        int ws = w + Wn / 2; if (ws >= Wn) ws -= Wn;
        maskT[e] = (float)mask[hs * Wn + ws] * (1.0f / (float)HWn);
    }
}

// ---------- row FFT (224 = 7*32), 8 rows/block, 64 threads, single wave ----------
// INVERSE=0: read P strip (row-major), coil-mul, FFT224 along w, write Y1T (transposed, h contig)
// INVERSE=1: read Y1T strip (transposed), IFFT224 along w, conj-coil-mul, write Y2 (row-major)
#define RPITCH 230
template<int INVERSE>
__global__ __launch_bounds__(64) void k_rowfft(const float2* __restrict__ src,
                                               const float2* __restrict__ coil,
                                               float2* __restrict__ Y1T,
                                               float2* __restrict__ Y2,
                                               const float2* __restrict__ twg,
                                               int chunkStart) {
    __shared__ float2 buf[8][RPITCH];
    __shared__ float2 tws[TW_N];
    int tid = threadIdx.x;
    int h0 = blockIdx.x * 8;
    int d = blockIdx.y, cz = blockIdx.z;
    for (int i = tid; i < TW_N; i += 64) tws[i] = twg[i];
    const float2* w32 = tws + TW_W32;
    const float2* w7  = tws + TW_W7;
    const float2* b224 = tws + TW_B224;
    size_t imgOff = ((size_t)cz * Dn + d) * (size_t)HWn;   // base of this (coil,slice) image
    const float2* cl = coil + (size_t)(chunkStart + cz) * HWn + (size_t)h0 * Wn;
    wsync();

    // ---- load ----
    if (!INVERSE) {
        const float2* inrow = src + (size_t)d * HWn + (size_t)h0 * Wn;
        for (int i = tid; i < 8 * 224; i += 64) {
            int r = i / 224, w = i - r * 224;
            buf[r][w] = cmul(inrow[r * Wn + w], cl[r * Wn + w]);   // coalesced rows
        }
    } else {
        const float2* inT = Y1T + imgOff + h0;   // + w*448 + r
        for (int i = tid; i < 8 * 224; i += 64) {
            int r = i & 7, w = i >> 3;           // lanes: r fastest -> 64B segments
            buf[r][w] = inT[(size_t)w * Hn + r];
        }
    }
    wsync();

    const float sign = INVERSE ? -1.f : 1.f;
    {   // stage 1: 56 tasks (8 rows x 7 n1)
        int rowA = tid & 7, n1A = tid >> 3;
        float2 x[32];
        if (tid < 56) {
#pragma unroll
            for (int n2 = 0; n2 < 32; ++n2) x[n2] = buf[rowA][n1A + 7 * n2];
            fft32(x, w32, sign);
        }
        wsync();
        if (tid < 56) {
#pragma unroll
            for (int i2 = 0; i2 < 32; ++i2) buf[rowA][33 * n1A + brev5(i2)] = x[i2];
        }
    }
    wsync();

    // stage 2: 256 tasks / 64 thr
    float2 res[4][7];
#pragma unroll
    for (int t = 0; t < 4; ++t) {
        int task = tid + t * 64;
        int row = task >> 5, k2 = task & 31;
        float2 base = b224[k2]; base.y *= sign;
        float2 tp[7]; twpow(tp, base);
        float2 Z[7];
#pragma unroll
        for (int n1 = 0; n1 < 7; ++n1) Z[n1] = cmul(buf[row][33 * n1 + k2], tp[n1]);
#pragma unroll
        for (int k1 = 0; k1 < 7; ++k1) {
            float2 s = Z[0];
#pragma unroll
            for (int n1 = 1; n1 < 7; ++n1) {
                float2 wv = w7[(n1 * k1) % 7]; wv.y *= sign;
                s = cfma(Z[n1], wv, s);
            }
            res[t][k1] = s;
        }
    }
    wsync();
#pragma unroll
    for (int t = 0; t < 4; ++t) {
        int task = tid + t * 64;
        int row = task >> 5, k2 = task & 31;
#pragma unroll
        for (int k1 = 0; k1 < 7; ++k1) buf[row][k2 + 32 * k1] = res[t][k1];
    }
    wsync();

    // ---- store ----
    if (!INVERSE) {
        float2* outT = Y1T + imgOff + h0;       // + w*448 + r
        for (int i = tid; i < 8 * 224; i += 64) {
            int r = i & 7, w = i >> 3;          // 64B segments
            outT[(size_t)w * Hn + r] = buf[r][w];
        }
    } else {
        float2* outp = Y2 + imgOff + (size_t)h0 * Wn;
        for (int i = tid; i < 8 * 224; i += 64) {
            int r = i / 224, w = i - r * 224;
            float2 v = buf[r][w];
            float2 c = cl[r * Wn + w];
            outp[r * Wn + w] = make_float2(fmaf(v.x, c.x, v.y * c.y),
                                           fmaf(v.y, c.x, -v.x * c.y));
        }
    }
}

// ---------- column FFT (448 = 14*32) + mask + IFFT fused, on Y1T (contiguous lines) ----------
// 4 lines/block, 64 threads, single wave, fully coalesced global I/O
#define CPITCH 462
__global__ __launch_bounds__(64) void k_colfft(float2* __restrict__ Y1T,
                                               const float* __restrict__ maskT,
                                               const float2* __restrict__ twg) {
    __shared__ float2 buf[4][CPITCH];
    __shared__ float2 tws[TW_N];
    int tid = threadIdx.x;
    int w0 = blockIdx.x * 4;
    int d = blockIdx.y, cz = blockIdx.z;
    for (int i = tid; i < TW_N; i += 64) tws[i] = twg[i];
    const float2* w32 = tws + TW_W32;
    const float2* w14 = tws + TW_W14;
    const float2* w7  = tws + TW_W7;
    const float2* b448 = tws + TW_B448;
    float2* img = Y1T + ((size_t)cz * Dn + d) * (size_t)HWn + (size_t)w0 * Hn;
    wsync();

    // load 4 contiguous lines (512B per instruction)
    for (int i = tid; i < 4 * 448; i += 64) {
        int l = i / 448, h = i - l * 448;
        buf[l][h] = img[(size_t)l * Hn + h];
    }
    wsync();

    int colA = tid & 3, n1A = tid >> 2;   // 56 active stage-1 tasks
    float2 x[32];
    for (int pass = 0; pass < 2; ++pass) {
        float sign = pass ? -1.f : 1.f;
        if (n1A < 14) {
#pragma unroll
            for (int n2 = 0; n2 < 32; ++n2) x[n2] = buf[colA][n1A + 14 * n2];
            fft32(x, w32, sign);
        }
        wsync();
        if (n1A < 14) {
#pragma unroll
            for (int i2 = 0; i2 < 32; ++i2) buf[colA][33 * n1A + brev5(i2)] = x[i2];
        }
        wsync();

        // stage 2: 128 tasks / 64 thr, DFT14 via even/odd 2x DFT7
        float2 res[2][14];
#pragma unroll
        for (int t = 0; t < 2; ++t) {
            int task = tid + t * 64;
            int l = task >> 5, k2 = task & 31;
            float2 base = b448[k2]; base.y *= sign;
            float2 tp[14]; twpow(tp, base);
            float2 Z[14];
#pragma unroll
            for (int n1 = 0; n1 < 14; ++n1) Z[n1] = cmul(buf[l][33 * n1 + k2], tp[n1]);
            float2 A[7], Bv[7];
#pragma unroll
            for (int j = 0; j < 7; ++j) {
                float2 sa = Z[0], sb = Z[1];
#pragma unroll
                for (int m = 1; m < 7; ++m) {
                    float2 wv = w7[(m * j) % 7]; wv.y *= sign;
                    sa = cfma(Z[2 * m], wv, sa);
                    sb = cfma(Z[2 * m + 1], wv, sb);
                }
                A[j] = sa; Bv[j] = sb;
            }
            const float* mcol = maskT + (size_t)(w0 + l) * Hn;
#pragma unroll
            for (int k1 = 0; k1 < 14; ++k1) {
                int j = k1 % 7;
                float2 wv = w14[k1]; wv.y *= sign;
                float2 s = cfma(Bv[j], wv, A[j]);
                if (pass == 0) {
                    float m = mcol[k2 + 32 * k1];   // coalesced: lanes vary k2
                    s.x *= m; s.y *= m;
                }
                res[t][k1] = s;
            }
        }
        wsync();
#pragma unroll
        for (int t = 0; t < 2; ++t) {
            int task = tid + t * 64;
            int l = task >> 5, k2 = task & 31;
#pragma unroll
            for (int k1 = 0; k1 < 14; ++k1) buf[l][k2 + 32 * k1] = res[t][k1];
        }
        wsync();
    }

    for (int i = tid; i < 4 * 448; i += 64) {
        int l = i / 448, h = i - l * 448;
        img[(size_t)l * Hn + h] = buf[l][h];
    }
}

// ---------- combine: q = mu*p + sum_c Y2[c]; last chunk: qp = sum q*conj(p) ----------
__global__ void k_combine(const float2* __restrict__ Y2, const float2* __restrict__ p,
                          float2* __restrict__ q, const float* __restrict__ miu,
                          double* __restrict__ S, int cc, int first, int last, int it) {
    float mu = fabsf(miu[0]);
    double ar = 0.0, ai = 0.0;
    for (int e = blockIdx.x * blockDim.x + threadIdx.x; e < DHWn; e += gridDim.x * blockDim.x) {
        float2 pv = make_float2(0.f, 0.f);
        float2 s;
        if (first) { pv = p[e]; s = make_float2(mu * pv.x, mu * pv.y); }
        else s = q[e];
        for (int cz = 0; cz < cc; ++cz) {
            float2 y = Y2[(size_t)cz * DHWn + e];
            s.x += y.x; s.y += y.y;
        }
        q[e] = s;
        if (last) {
            if (!first) pv = p[e];
            ar += (double)(s.x * pv.x + s.y * pv.y);
            ai += (double)(s.y * pv.x - s.x * pv.y);
        }
    }
    if (last) {
        ar = waveReduce(ar);
        ai = waveReduce(ai);
        if ((threadIdx.x & 63) == 0) {
            atomicAdd(&S[8 + it], ar);
            atomicAdd(&S[16 + it], ai);
        }
    }
}

__global__ void k_update_br(const double* __restrict__ Sin, double* __restrict__ S, int it,
                            const float2* __restrict__ p, const float2* __restrict__ q,
                            float2* __restrict__ b, float2* __restrict__ r) {
    double rr = Sin[it], qr = Sin[8 + it], qi = Sin[16 + it];
    double den = qr * qr + qi * qi;
    float arf = (float)(rr * qr / den);
    float aif = (float)(-rr * qi / den);
    double acc = 0.0;
    for (int e = blockIdx.x * blockDim.x + threadIdx.x; e < DHWn; e += gridDim.x * blockDim.x) {
        float2 pv = p[e], qv = q[e], bv = b[e], rv = r[e];
        bv.x += arf * pv.x - aif * pv.y;
        bv.y += arf * pv.y + aif * pv.x;
        b[e] = bv;
        rv.x -= arf * qv.x - aif * qv.y;
        rv.y -= arf * qv.y + aif * qv.x;
        r[e] = rv;
        acc += (double)rv.x * rv.x + (double)rv.y * rv.y;
    }
    acc = waveReduce(acc);
    if ((threadIdx.x & 63) == 0) atomicAdd(&S[it + 1], acc);
}

__global__ void k_update_p(const double* __restrict__ S, int it,
                           const float2* __restrict__ r, float2* __restrict__ p) {
    float beta = (float)(S[it + 1] / S[it]);
    for (int e = blockIdx.x * blockDim.x + threadIdx.x; e < DHWn; e += gridDim.x * blockDim.x) {
        float2 rv = r[e], pv = p[e];
        p[e] = make_float2(fmaf(beta, pv.x, rv.x), fmaf(beta, pv.y, rv.y));
    }
}

__global__ void k_output(const float2* __restrict__ b, float* __restrict__ out) {
    for (int e = blockIdx.x * blockDim.x + threadIdx.x; e < DHWn; e += gridDim.x * blockDim.x) {
        int d = e / HWn, rem = e - d * HWn;
        int h = rem / Wn, w = rem - h * Wn;
        int hs = h + Hn / 2; if (hs >= Hn) hs -= Hn;
        int ws = w + Wn / 2; if (ws >= Wn) ws -= Wn;
        float2 v = b[d * HWn + hs * Wn + ws];
        out[e] = v.x;
        out[DHWn + e] = v.y;
    }
}

extern "C" void kernel_launch(void* const* d_in, const int* in_sizes, int n_in,
                              void* d_out, int out_size, void* d_ws, size_t ws_size,
                              hipStream_t stream) {
    const float* z      = (const float*)d_in[0];
    const float* zf     = (const float*)d_in[1];
    const float* coil_r = (const float*)d_in[2];
    const float* coil_i = (const float*)d_in[3];
    const int*   maskp  = (const int*)d_in[4];
    const float* miu    = (const float*)d_in[5];
    float* out = (float*)d_out;

    char* w = (char*)d_ws;
    size_t off = 0;
    auto carve = [&](size_t bytes) -> void* {
        void* ptr = w + off;
        off += (bytes + 511) & ~(size_t)511;
        return ptr;
    };
    float2* P     = (float2*)carve((size_t)DHWn * 8);
    float2* R     = (float2*)carve((size_t)DHWn * 8);
    float2* Bv    = (float2*)carve((size_t)DHWn * 8);
    float2* Q     = (float2*)carve((size_t)DHWn * 8);
    float2* COIL  = (float2*)carve((size_t)Cn * HWn * 8);
    float*  MASKT = (float*)carve((size_t)HWn * 4);
    float2* TWS   = (float2*)carve(TW_N * 8);
    double* S     = (double*)carve(64 * 8);

    size_t imgSet = (size_t)DHWn * 8;   // one coil-slot (12 slices)
    int cc = 1;
    {
        const int opts[4] = {10, 5, 2, 1};
        for (int i = 0; i < 4; ++i) {
            if (off + 2 * (size_t)opts[i] * imgSet <= ws_size) { cc = opts[i]; break; }
        }
    }
    float2* Y1T = (float2*)carve((size_t)cc * imgSet);   // transposed staging [c][d][w][h]
    float2* Y2  = (float2*)carve((size_t)cc * imgSet);   // row-major staging  [c][d][h][w]
    int nch = Cn / cc;

    k_init_misc<<<1, 128, 0, stream>>>(TWS, S);
    k_build_p<<<1024, 256, 0, stream>>>(z, zf, miu, P, R, Bv, S);
    k_build_coil<<<1024, 256, 0, stream>>>(coil_r, coil_i, COIL);
    k_build_mask<<<512, 256, 0, stream>>>(maskp, MASKT);

    for (int it = 0; it < 5; ++it) {
        for (int ch = 0; ch < nch; ++ch) {
            int cs = ch * cc;
            dim3 gr(Hn / 8, Dn, cc);   // 56 x 12 x cc
            dim3 gc(Wn / 4, Dn, cc);   // 56 x 12 x cc
            k_rowfft<0><<<gr, 64, 0, stream>>>(P, COIL, Y1T, Y2, TWS, cs);
            k_colfft<<<gc, 64, 0, stream>>>(Y1T, MASKT, TWS);
            k_rowfft<1><<<gr, 64, 0, stream>>>(P, COIL, Y1T, Y2, TWS, cs);
            k_combine<<<1024, 256, 0, stream>>>(Y2, P, Q, miu, S, cc,
                                                ch == 0 ? 1 : 0, ch == nch - 1 ? 1 : 0, it);
        }
        k_update_br<<<1024, 256, 0, stream>>>(S, S, it, P, Q, Bv, R);
        if (it < 4) k_update_p<<<1024, 256, 0, stream>>>(S, it, R, P);
    }
    k_output<<<1024, 256, 0, stream>>>(Bv, out);
}

// Round 5
// 1645.045 us; speedup vs baseline: 1.5834x; 1.1441x over previous
//
#include <hip/hip_runtime.h>
#include <math.h>

// Problem constants (fixed shapes from setup_inputs)
#define Dn   12
#define Hn   448
#define Wn   224
#define HWn  (Hn*Wn)        // 100352
#define DHWn (Dn*HWn)       // 1204224
#define Cn   10

// Twiddle table (float2 in global, copied to LDS per block):
#define TW_W32   0     // 16: W32^j
#define TW_W14   16    // 14: W14^j
#define TW_W7    30    // 7:  W7^j
#define TW_B448  37    // 32: W448^j (j<32)
#define TW_B224  69    // 32: W224^j (j<32)
#define TW_B448L 101   // 64: W448^a (a<64)  -- for lane-FFT col kernel
#define TW_W64   165   // 32: W64^j (j<32)
#define TW_N     101   // rowfft loads this prefix
#define TW_N2    197   // colfft loads all

// ---------- complex helpers ----------
__device__ __forceinline__ float2 cmul(float2 a, float2 b) {
    return make_float2(fmaf(a.x, b.x, -a.y * b.y), fmaf(a.x, b.y, a.y * b.x));
}
__device__ __forceinline__ float2 cfma(float2 a, float2 b, float2 acc) {
    acc.x = fmaf(a.x, b.x, fmaf(-a.y, b.y, acc.x));
    acc.y = fmaf(a.x, b.y, fmaf(a.y, b.x, acc.y));
    return acc;
}
__device__ __forceinline__ float2 cadd(float2 a, float2 b) { return make_float2(a.x + b.x, a.y + b.y); }
__device__ __forceinline__ float2 csub(float2 a, float2 b) { return make_float2(a.x - b.x, a.y - b.y); }
__host__ __device__ constexpr int brev5(int i) {
    return ((i & 1) << 4) | ((i & 2) << 2) | (i & 4) | ((i & 8) >> 2) | ((i & 16) >> 4);
}
// single-wave blocks: compiler fence only; DS pipe is in-order per wave
__device__ __forceinline__ void wsync() { __builtin_amdgcn_wave_barrier(); }

__device__ __forceinline__ float2 shflx2(float2 v, int m) {
    return make_float2(__shfl_xor(v.x, m, 64), __shfl_xor(v.y, m, 64));
}

__device__ __forceinline__ double waveReduce(double v) {
#pragma unroll
    for (int o = 32; o > 0; o >>= 1) v += __shfl_down(v, o, 64);
    return v;
}

// log-depth twiddle powers tp[j] = base^j (depth <= 4)
template<int NP>
__device__ __forceinline__ void twpow(float2 (&tp)[NP], float2 base) {
    tp[0] = make_float2(1.f, 0.f);
    tp[1] = base;
#pragma unroll
    for (int j = 2; j < NP; ++j) tp[j] = cmul(tp[j >> 1], tp[j - (j >> 1)]);
}

// In-register 32-point DIF FFT using LDS w32 table (broadcast reads).
__device__ __forceinline__ void fft32(float2 (&x)[32], const float2* __restrict__ w32, float sign) {
#pragma unroll
    for (int s = 0; s < 5; ++s) {
        const int L = 32 >> s, half = L >> 1;
#pragma unroll
        for (int b0 = 0; b0 < 32; b0 += L) {
#pragma unroll
            for (int j = 0; j < half; ++j) {
                float2 a = x[b0 + j], c = x[b0 + j + half];
                x[b0 + j] = cadd(a, c);
                float2 t = csub(a, c);
                float2 w = w32[j << s]; w.y *= sign;
                x[b0 + j + half] = cmul(t, w);
            }
        }
    }
}

// ---------- init kernels ----------
__global__ void k_init_misc(float2* __restrict__ tws, double* __restrict__ S) {
    int t = threadIdx.x;  // 256 threads
    const double PI2 = 6.283185307179586476925287;
    if (t < 16)             { double s, c; sincos(-(PI2 * t) / 32.0,  &s, &c); tws[TW_W32 + t]  = make_float2((float)c, (float)s); }
    if (t >= 16 && t < 30)  { int j = t - 16; double s, c; sincos(-(PI2 * j) / 14.0, &s, &c); tws[TW_W14 + j] = make_float2((float)c, (float)s); }
    if (t >= 30 && t < 37)  { int j = t - 30; double s, c; sincos(-(PI2 * j) / 7.0,  &s, &c); tws[TW_W7 + j]  = make_float2((float)c, (float)s); }
    if (t >= 37 && t < 69)  { int j = t - 37; double s, c; sincos(-(PI2 * j) / 448.0, &s, &c); tws[TW_B448 + j] = make_float2((float)c, (float)s); }
    if (t >= 69 && t < 101) { int j = t - 69; double s, c; sincos(-(PI2 * j) / 224.0, &s, &c); tws[TW_B224 + j] = make_float2((float)c, (float)s); }
    if (t >= 101 && t < 165){ int j = t - 101; double s, c; sincos(-(PI2 * j) / 448.0, &s, &c); tws[TW_B448L + j] = make_float2((float)c, (float)s); }
    if (t >= 165 && t < 197){ int j = t - 165; double s, c; sincos(-(PI2 * j) / 64.0,  &s, &c); tws[TW_W64 + j]  = make_float2((float)c, (float)s); }
    if (t >= 197 && t < 229) S[t - 197] = 0.0;
}

__global__ void k_build_p(const float* __restrict__ z, const float* __restrict__ zf,
                          const float* __restrict__ miu,
                          float2* __restrict__ p, float2* __restrict__ r, float2* __restrict__ b,
                          double* __restrict__ S) {
    float mu = fabsf(miu[0]);
    double acc = 0.0;
    for (int e = blockIdx.x * blockDim.x + threadIdx.x; e < DHWn; e += gridDim.x * blockDim.x) {
        int d = e / HWn, rem = e - d * HWn;
        int h = rem / Wn, w = rem - h * Wn;
        int hs = h + Hn / 2; if (hs >= Hn) hs -= Hn;
        int ws = w + Wn / 2; if (ws >= Wn) ws -= Wn;
        int src = d * HWn + hs * Wn + ws;
        float pr = fmaf(mu, z[src], zf[src]);
        float pi = fmaf(mu, z[DHWn + src], zf[DHWn + src]);
        float2 v = make_float2(pr, pi);
        p[e] = v; r[e] = v; b[e] = make_float2(0.f, 0.f);
        acc += (double)pr * pr + (double)pi * pi;
    }
    acc = waveReduce(acc);
    if ((threadIdx.x & 63) == 0) atomicAdd(&S[0], acc);
}

__global__ void k_build_coil(const float* __restrict__ cr, const float* __restrict__ ci,
                             float2* __restrict__ coil) {
    for (int e = blockIdx.x * blockDim.x + threadIdx.x; e < Cn * HWn; e += gridDim.x * blockDim.x) {
        int c = e / HWn, rem = e - c * HWn;
        int h = rem / Wn, w = rem - h * Wn;
        int hs = h + Hn / 2; if (hs >= Hn) hs -= Hn;
        int ws = w + Wn / 2; if (ws >= Wn) ws -= Wn;
        int src = c * HWn + hs * Wn + ws;
        coil[e] = make_float2(cr[src], ci[src]);
    }
}

// transposed, shifted, scaled mask: maskT[w*448 + h]
__global__ void k_build_mask(const int* __restrict__ mask, float* __restrict__ maskT) {
    for (int e = blockIdx.x * blockDim.x + threadIdx.x; e < HWn; e += gridDim.x * blockDim.x) {
        int w = e / Hn, h = e - w * Hn;
        int hs = h + Hn / 2; if (hs >= Hn) hs -= Hn;
        int ws = w + Wn / 2; if (ws >= Wn) ws -= Wn;
        maskT[e] = (float)mask[hs * Wn + ws] * (1.0f / (float)HWn);
    }
}

// ---------- row FFT (224 = 7*32), 8 rows/block, 64 threads, single wave ----------
// INVERSE=0: read P strip (row-major), coil-mul, FFT224 along w, write Y1T (transposed, h contig)
// INVERSE=1: read Y1T strip (transposed), IFFT224 along w, conj-coil-mul, write Y2 (row-major)
#define RPITCH 230
template<int INVERSE>
__global__ __launch_bounds__(64) void k_rowfft(const float2* __restrict__ src,
                                               const float2* __restrict__ coil,
                                               float2* __restrict__ Y1T,
                                               float2* __restrict__ Y2,
                                               const float2* __restrict__ twg,
                                               int chunkStart) {
    __shared__ float2 buf[8][RPITCH];
    __shared__ float2 tws[TW_N];
    int tid = threadIdx.x;
    int h0 = blockIdx.x * 8;
    int d = blockIdx.y, cz = blockIdx.z;
    for (int i = tid; i < TW_N; i += 64) tws[i] = twg[i];
    const float2* w32 = tws + TW_W32;
    const float2* w7  = tws + TW_W7;
    const float2* b224 = tws + TW_B224;
    size_t imgOff = ((size_t)cz * Dn + d) * (size_t)HWn;   // base of this (coil,slice) image
    const float2* cl = coil + (size_t)(chunkStart + cz) * HWn + (size_t)h0 * Wn;
    wsync();

    // ---- load ----
    if (!INVERSE) {
        const float2* inrow = src + (size_t)d * HWn + (size_t)h0 * Wn;
        for (int i = tid; i < 8 * 224; i += 64) {
            int r = i / 224, w = i - r * 224;
            buf[r][w] = cmul(inrow[r * Wn + w], cl[r * Wn + w]);   // coalesced rows
        }
    } else {
        const float2* inT = Y1T + imgOff + h0;   // + w*448 + r
        for (int i = tid; i < 8 * 224; i += 64) {
            int r = i & 7, w = i >> 3;           // lanes: r fastest -> 64B segments
            buf[r][w] = inT[(size_t)w * Hn + r];
        }
    }
    wsync();

    const float sign = INVERSE ? -1.f : 1.f;
    {   // stage 1: 56 tasks (8 rows x 7 n1)
        int rowA = tid & 7, n1A = tid >> 3;
        float2 x[32];
        if (tid < 56) {
#pragma unroll
            for (int n2 = 0; n2 < 32; ++n2) x[n2] = buf[rowA][n1A + 7 * n2];
            fft32(x, w32, sign);
        }
        wsync();
        if (tid < 56) {
#pragma unroll
            for (int i2 = 0; i2 < 32; ++i2) buf[rowA][33 * n1A + brev5(i2)] = x[i2];
        }
    }
    wsync();

    // stage 2: 256 tasks / 64 thr
    float2 res[4][7];
#pragma unroll
    for (int t = 0; t < 4; ++t) {
        int task = tid + t * 64;
        int row = task >> 5, k2 = task & 31;
        float2 base = b224[k2]; base.y *= sign;
        float2 tp[7]; twpow(tp, base);
        float2 Z[7];
#pragma unroll
        for (int n1 = 0; n1 < 7; ++n1) Z[n1] = cmul(buf[row][33 * n1 + k2], tp[n1]);
#pragma unroll
        for (int k1 = 0; k1 < 7; ++k1) {
            float2 s = Z[0];
#pragma unroll
            for (int n1 = 1; n1 < 7; ++n1) {
                float2 wv = w7[(n1 * k1) % 7]; wv.y *= sign;
                s = cfma(Z[n1], wv, s);
            }
            res[t][k1] = s;
        }
    }
    wsync();
#pragma unroll
    for (int t = 0; t < 4; ++t) {
        int task = tid + t * 64;
        int row = task >> 5, k2 = task & 31;
#pragma unroll
        for (int k1 = 0; k1 < 7; ++k1) buf[row][k2 + 32 * k1] = res[t][k1];
    }
    wsync();

    // ---- store ----
    if (!INVERSE) {
        float2* outT = Y1T + imgOff + h0;       // + w*448 + r
        for (int i = tid; i < 8 * 224; i += 64) {
            int r = i & 7, w = i >> 3;          // 64B segments
            outT[(size_t)w * Hn + r] = buf[r][w];
        }
    } else {
        float2* outp = Y2 + imgOff + (size_t)h0 * Wn;
        for (int i = tid; i < 8 * 224; i += 64) {
            int r = i / 224, w = i - r * 224;
            float2 v = buf[r][w];
            float2 c = cl[r * Wn + w];
            outp[r * Wn + w] = make_float2(fmaf(v.x, c.x, v.y * c.y),
                                           fmaf(v.y, c.x, -v.x * c.y));
        }
    }
}

// ---------- column FFT448 + mask + IFFT448, pure register lane-FFT ----------
// 448 = 7 x 64: per-lane DFT7 (registers), cross-lane FFT64 (shfl_xor butterflies).
// One wave per contiguous Y1T line; 4 independent waves per block; LDS = twiddle table only.
__global__ __launch_bounds__(256) void k_colfft(float2* __restrict__ Y1T,
                                                const float* __restrict__ maskT,
                                                const float2* __restrict__ twg) {
    __shared__ float2 tws[TW_N2];
    int tid = threadIdx.x;
    int lane = tid & 63, wv = tid >> 6;
    for (int i = tid; i < TW_N2; i += 256) tws[i] = twg[i];
    __syncthreads();   // once: table visible to all 4 waves

    const float2* w7t  = tws + TW_W7;
    const float2* w64t = tws + TW_W64;
    const float2* b448l = tws + TW_B448L;

    int w = blockIdx.x * 4 + wv;
    int d = blockIdx.y, cz = blockIdx.z;
    float2* line = Y1T + ((size_t)cz * Dn + d) * (size_t)HWn + (size_t)w * Hn;

    // load: lane a holds x[64b + a], b=0..6 (512B coalesced per b)
    float2 xb[7];
#pragma unroll
    for (int b = 0; b < 7; ++b) xb[b] = line[64 * b + lane];

    // ---- forward DFT7 per lane: y[d7] = sum_b xb[b] * W7^{b*d7} ----
    float2 y[7];
#pragma unroll
    for (int d7 = 0; d7 < 7; ++d7) {
        float2 s = xb[0];
#pragma unroll
        for (int b = 1; b < 7; ++b) {
            float2 wq = w7t[(b * d7) % 7];
            s = cfma(xb[b], wq, s);
        }
        y[d7] = s;
    }
    // ---- twiddle W448^{lane*d7} ----
    float2 tp[7]; twpow(tp, b448l[lane]);
#pragma unroll
    for (int d7 = 1; d7 < 7; ++d7) y[d7] = cmul(y[d7], tp[d7]);

    // ---- FFT64 across lanes, DIF (output bit-reversed in lane index) ----
#pragma unroll
    for (int s = 0; s < 6; ++s) {
        int dist = 32 >> s;
        float2 wst = w64t[(lane & (dist - 1)) << s];
        bool hi = (lane & dist) != 0;
#pragma unroll
        for (int d7 = 0; d7 < 7; ++d7) {
            float2 t = shflx2(y[d7], dist);
            float2 sum = cadd(y[d7], t);
            float2 dif = cmul(csub(t, y[d7]), wst);   // (u - v)*w for hi lane (t=u there)
            y[d7] = hi ? dif : sum;
        }
    }

    // ---- mask: lane holds X[7*brev6(lane) + d7] ----
    int rb = (brev5(lane & 31) << 1) | (lane >> 5);
    const float* mrow = maskT + (size_t)w * Hn + 7 * rb;
#pragma unroll
    for (int d7 = 0; d7 < 7; ++d7) {
        float m = mrow[d7];
        y[d7].x *= m; y[d7].y *= m;
    }

    // ---- inverse FFT64 across lanes, DIT (consumes bit-reversed, outputs natural) ----
#pragma unroll
    for (int s = 0; s < 6; ++s) {
        int dist = 1 << s;
        float2 wst = w64t[(lane & (dist - 1)) << (5 - s)];
        wst.y = -wst.y;                                   // conj
        bool hi = (lane & dist) != 0;
#pragma unroll
        for (int d7 = 0; d7 < 7; ++d7) {
            float2 t = shflx2(y[d7], dist);
            float2 uu = hi ? t : y[d7];
            float2 vv = hi ? y[d7] : t;
            float2 wtv = cmul(vv, wst);
            y[d7] = hi ? csub(uu, wtv) : cadd(uu, wtv);
        }
    }
    // ---- conj twiddle ----
#pragma unroll
    for (int d7 = 1; d7 < 7; ++d7) {
        float2 c = make_float2(tp[d7].x, -tp[d7].y);
        y[d7] = cmul(y[d7], c);
    }
    // ---- inverse DFT7 per lane: xb[b] = sum_d7 y[d7] * W7^{-b*d7} ----
#pragma unroll
    for (int b = 0; b < 7; ++b) {
        float2 s = y[0];
#pragma unroll
        for (int d7 = 1; d7 < 7; ++d7) {
            float2 wq = w7t[(b * d7) % 7]; wq.y = -wq.y;
            s = cfma(y[d7], wq, s);
        }
        xb[b] = s;
    }
    // store (coalesced)
#pragma unroll
    for (int b = 0; b < 7; ++b) line[64 * b + lane] = xb[b];
}

// ---------- combine: q = mu*p + sum_c Y2[c]; last chunk: qp = sum q*conj(p) ----------
__global__ void k_combine(const float2* __restrict__ Y2, const float2* __restrict__ p,
                          float2* __restrict__ q, const float* __restrict__ miu,
                          double* __restrict__ S, int cc, int first, int last, int it) {
    float mu = fabsf(miu[0]);
    double ar = 0.0, ai = 0.0;
    for (int e = blockIdx.x * blockDim.x + threadIdx.x; e < DHWn; e += gridDim.x * blockDim.x) {
        float2 pv = make_float2(0.f, 0.f);
        float2 s;
        if (first) { pv = p[e]; s = make_float2(mu * pv.x, mu * pv.y); }
        else s = q[e];
        for (int cz = 0; cz < cc; ++cz) {
            float2 yv = Y2[(size_t)cz * DHWn + e];
            s.x += yv.x; s.y += yv.y;
        }
        q[e] = s;
        if (last) {
            if (!first) pv = p[e];
            ar += (double)(s.x * pv.x + s.y * pv.y);
            ai += (double)(s.y * pv.x - s.x * pv.y);
        }
    }
    if (last) {
        ar = waveReduce(ar);
        ai = waveReduce(ai);
        if ((threadIdx.x & 63) == 0) {
            atomicAdd(&S[8 + it], ar);
            atomicAdd(&S[16 + it], ai);
        }
    }
}

__global__ void k_update_br(const double* __restrict__ Sin, double* __restrict__ S, int it,
                            const float2* __restrict__ p, const float2* __restrict__ q,
                            float2* __restrict__ b, float2* __restrict__ r) {
    double rr = Sin[it], qr = Sin[8 + it], qi = Sin[16 + it];
    double den = qr * qr + qi * qi;
    float arf = (float)(rr * qr / den);
    float aif = (float)(-rr * qi / den);
    double acc = 0.0;
    for (int e = blockIdx.x * blockDim.x + threadIdx.x; e < DHWn; e += gridDim.x * blockDim.x) {
        float2 pv = p[e], qv = q[e], bv = b[e], rv = r[e];
        bv.x += arf * pv.x - aif * pv.y;
        bv.y += arf * pv.y + aif * pv.x;
        b[e] = bv;
        rv.x -= arf * qv.x - aif * qv.y;
        rv.y -= arf * qv.y + aif * qv.x;
        r[e] = rv;
        acc += (double)rv.x * rv.x + (double)rv.y * rv.y;
    }
    acc = waveReduce(acc);
    if ((threadIdx.x & 63) == 0) atomicAdd(&S[it + 1], acc);
}

__global__ void k_update_p(const double* __restrict__ S, int it,
                           const float2* __restrict__ r, float2* __restrict__ p) {
    float beta = (float)(S[it + 1] / S[it]);
    for (int e = blockIdx.x * blockDim.x + threadIdx.x; e < DHWn; e += gridDim.x * blockDim.x) {
        float2 rv = r[e], pv = p[e];
        p[e] = make_float2(fmaf(beta, pv.x, rv.x), fmaf(beta, pv.y, rv.y));
    }
}

__global__ void k_output(const float2* __restrict__ b, float* __restrict__ out) {
    for (int e = blockIdx.x * blockDim.x + threadIdx.x; e < DHWn; e += gridDim.x * blockDim.x) {
        int d = e / HWn, rem = e - d * HWn;
        int h = rem / Wn, w = rem - h * Wn;
        int hs = h + Hn / 2; if (hs >= Hn) hs -= Hn;
        int ws = w + Wn / 2; if (ws >= Wn) ws -= Wn;
        float2 v = b[d * HWn + hs * Wn + ws];
        out[e] = v.x;
        out[DHWn + e] = v.y;
    }
}

extern "C" void kernel_launch(void* const* d_in, const int* in_sizes, int n_in,
                              void* d_out, int out_size, void* d_ws, size_t ws_size,
                              hipStream_t stream) {
    const float* z      = (const float*)d_in[0];
    const float* zf     = (const float*)d_in[1];
    const float* coil_r = (const float*)d_in[2];
    const float* coil_i = (const float*)d_in[3];
    const int*   maskp  = (const int*)d_in[4];
    const float* miu    = (const float*)d_in[5];
    float* out = (float*)d_out;

    char* w = (char*)d_ws;
    size_t off = 0;
    auto carve = [&](size_t bytes) -> void* {
        void* ptr = w + off;
        off += (bytes + 511) & ~(size_t)511;
        return ptr;
    };
    float2* P     = (float2*)carve((size_t)DHWn * 8);
    float2* R     = (float2*)carve((size_t)DHWn * 8);
    float2* Bv    = (float2*)carve((size_t)DHWn * 8);
    float2* Q     = (float2*)carve((size_t)DHWn * 8);
    float2* COIL  = (float2*)carve((size_t)Cn * HWn * 8);
    float*  MASKT = (float*)carve((size_t)HWn * 4);
    float2* TWS   = (float2*)carve(TW_N2 * 8);
    double* S     = (double*)carve(64 * 8);

    size_t imgSet = (size_t)DHWn * 8;   // one coil-slot (12 slices)
    int cc = 1;
    {
        const int opts[4] = {10, 5, 2, 1};
        for (int i = 0; i < 4; ++i) {
            if (off + 2 * (size_t)opts[i] * imgSet <= ws_size) { cc = opts[i]; break; }
        }
    }
    float2* Y1T = (float2*)carve((size_t)cc * imgSet);   // transposed staging [c][d][w][h]
    float2* Y2  = (float2*)carve((size_t)cc * imgSet);   // row-major staging  [c][d][h][w]
    int nch = Cn / cc;

    k_init_misc<<<1, 256, 0, stream>>>(TWS, S);
    k_build_p<<<1024, 256, 0, stream>>>(z, zf, miu, P, R, Bv, S);
    k_build_coil<<<1024, 256, 0, stream>>>(coil_r, coil_i, COIL);
    k_build_mask<<<512, 256, 0, stream>>>(maskp, MASKT);

    for (int it = 0; it < 5; ++it) {
        for (int ch = 0; ch < nch; ++ch) {
            int cs = ch * cc;
            dim3 gr(Hn / 8, Dn, cc);   // 56 x 12 x cc, 64-thr single-wave blocks
            dim3 gc(Wn / 4, Dn, cc);   // 56 x 12 x cc, 256-thr (4 indep waves)
            k_rowfft<0><<<gr, 64, 0, stream>>>(P, COIL, Y1T, Y2, TWS, cs);
            k_colfft<<<gc, 256, 0, stream>>>(Y1T, MASKT, TWS);
            k_rowfft<1><<<gr, 64, 0, stream>>>(P, COIL, Y1T, Y2, TWS, cs);
            k_combine<<<1024, 256, 0, stream>>>(Y2, P, Q, miu, S, cc,
                                                ch == 0 ? 1 : 0, ch == nch - 1 ? 1 : 0, it);
        }
        k_update_br<<<1024, 256, 0, stream>>>(S, S, it, P, Q, Bv, R);
        if (it < 4) k_update_p<<<1024, 256, 0, stream>>>(S, it, R, P);
    }
    k_output<<<1024, 256, 0, stream>>>(Bv, out);
}

// Round 6
// 1283.705 us; speedup vs baseline: 2.0290x; 1.2815x over previous
//
#include <hip/hip_runtime.h>
#include <math.h>

// Problem constants (fixed shapes from setup_inputs)
#define Dn   12
#define Hn   448
#define Wn   224
#define HWn  (Hn*Wn)        // 100352
#define DHWn (Dn*HWn)       // 1204224
#define Cn   10

// Twiddle table (float2 in global):
#define TW_W32   0     // 16: W32^j
#define TW_W14   16    // 14: W14^j (unused, kept for layout stability)
#define TW_W7    30    // 7:  W7^j
#define TW_B448  37    // 32: W448^j (unused)
#define TW_B224  69    // 32: W224^j (j<32)
#define TW_B448L 101   // 64: W448^a (a<64)  -- colfft lane twiddle
#define TW_W64   165   // 32: W64^j (j<32)
#define TW_N2    197

// ---------- complex helpers ----------
__device__ __forceinline__ float2 cmul(float2 a, float2 b) {
    return make_float2(fmaf(a.x, b.x, -a.y * b.y), fmaf(a.x, b.y, a.y * b.x));
}
__device__ __forceinline__ float2 cfma(float2 a, float2 b, float2 acc) {
    acc.x = fmaf(a.x, b.x, fmaf(-a.y, b.y, acc.x));
    acc.y = fmaf(a.x, b.y, fmaf(a.y, b.x, acc.y));
    return acc;
}
__device__ __forceinline__ float2 cadd(float2 a, float2 b) { return make_float2(a.x + b.x, a.y + b.y); }
__device__ __forceinline__ float2 csub(float2 a, float2 b) { return make_float2(a.x - b.x, a.y - b.y); }
__host__ __device__ constexpr int brev5(int i) {
    return ((i & 1) << 4) | ((i & 2) << 2) | (i & 4) | ((i & 8) >> 2) | ((i & 16) >> 4);
}

__device__ __forceinline__ float2 shflx2(float2 v, int m) {
    return make_float2(__shfl_xor(v.x, m, 64), __shfl_xor(v.y, m, 64));
}

__device__ __forceinline__ double waveReduce(double v) {
#pragma unroll
    for (int o = 32; o > 0; o >>= 1) v += __shfl_down(v, o, 64);
    return v;
}

// log-depth twiddle powers tp[j] = base^j (depth <= 4)
template<int NP>
__device__ __forceinline__ void twpow(float2 (&tp)[NP], float2 base) {
    tp[0] = make_float2(1.f, 0.f);
    tp[1] = base;
#pragma unroll
    for (int j = 2; j < NP; ++j) tp[j] = cmul(tp[j >> 1], tp[j - (j >> 1)]);
}

// ---------- init kernels ----------
__global__ void k_init_misc(float2* __restrict__ tws, double* __restrict__ S) {
    int t = threadIdx.x;  // 256 threads
    const double PI2 = 6.283185307179586476925287;
    if (t < 16)             { double s, c; sincos(-(PI2 * t) / 32.0,  &s, &c); tws[TW_W32 + t]  = make_float2((float)c, (float)s); }
    if (t >= 16 && t < 30)  { int j = t - 16; double s, c; sincos(-(PI2 * j) / 14.0, &s, &c); tws[TW_W14 + j] = make_float2((float)c, (float)s); }
    if (t >= 30 && t < 37)  { int j = t - 30; double s, c; sincos(-(PI2 * j) / 7.0,  &s, &c); tws[TW_W7 + j]  = make_float2((float)c, (float)s); }
    if (t >= 37 && t < 69)  { int j = t - 37; double s, c; sincos(-(PI2 * j) / 448.0, &s, &c); tws[TW_B448 + j] = make_float2((float)c, (float)s); }
    if (t >= 69 && t < 101) { int j = t - 69; double s, c; sincos(-(PI2 * j) / 224.0, &s, &c); tws[TW_B224 + j] = make_float2((float)c, (float)s); }
    if (t >= 101 && t < 165){ int j = t - 101; double s, c; sincos(-(PI2 * j) / 448.0, &s, &c); tws[TW_B448L + j] = make_float2((float)c, (float)s); }
    if (t >= 165 && t < 197){ int j = t - 165; double s, c; sincos(-(PI2 * j) / 64.0,  &s, &c); tws[TW_W64 + j]  = make_float2((float)c, (float)s); }
    if (t >= 197 && t < 229) S[t - 197] = 0.0;
}

__global__ void k_build_p(const float* __restrict__ z, const float* __restrict__ zf,
                          const float* __restrict__ miu,
                          float2* __restrict__ p, float2* __restrict__ r, float2* __restrict__ b,
                          double* __restrict__ S) {
    float mu = fabsf(miu[0]);
    double acc = 0.0;
    for (int e = blockIdx.x * blockDim.x + threadIdx.x; e < DHWn; e += gridDim.x * blockDim.x) {
        int d = e / HWn, rem = e - d * HWn;
        int h = rem / Wn, w = rem - h * Wn;
        int hs = h + Hn / 2; if (hs >= Hn) hs -= Hn;
        int ws = w + Wn / 2; if (ws >= Wn) ws -= Wn;
        int src = d * HWn + hs * Wn + ws;
        float pr = fmaf(mu, z[src], zf[src]);
        float pi = fmaf(mu, z[DHWn + src], zf[DHWn + src]);
        float2 v = make_float2(pr, pi);
        p[e] = v; r[e] = v; b[e] = make_float2(0.f, 0.f);
        acc += (double)pr * pr + (double)pi * pi;
    }
    acc = waveReduce(acc);
    if ((threadIdx.x & 63) == 0) atomicAdd(&S[0], acc);
}

__global__ void k_build_coil(const float* __restrict__ cr, const float* __restrict__ ci,
                             float2* __restrict__ coil) {
    for (int e = blockIdx.x * blockDim.x + threadIdx.x; e < Cn * HWn; e += gridDim.x * blockDim.x) {
        int c = e / HWn, rem = e - c * HWn;
        int h = rem / Wn, w = rem - h * Wn;
        int hs = h + Hn / 2; if (hs >= Hn) hs -= Hn;
        int ws = w + Wn / 2; if (ws >= Wn) ws -= Wn;
        int src = c * HWn + hs * Wn + ws;
        coil[e] = make_float2(cr[src], ci[src]);
    }
}

// permuted + shifted + scaled mask: maskP[L*448 + h], where line L holds true
// frequency column w(L) = 7*brev5(L&31) + (L>>5)  (matches rowfft0's output order)
__global__ void k_build_mask(const int* __restrict__ mask, float* __restrict__ maskP) {
    for (int e = blockIdx.x * blockDim.x + threadIdx.x; e < HWn; e += gridDim.x * blockDim.x) {
        int L = e / Hn, h = e - L * Hn;
        int w = 7 * brev5(L & 31) + (L >> 5);
        int hs = h + Hn / 2; if (hs >= Hn) hs -= Hn;
        int ws = w + Wn / 2; if (ws >= Wn) ws -= Wn;
        maskP[e] = (float)mask[hs * Wn + ws] * (1.0f / (float)HWn);
    }
}

// ---------- forward row FFT (224 = 7*32 lane-FFT), coil-mul, write Y1T lines ----------
// Block 256 = 4 waves, 8 rows (wave wv: rows 2wv + (lane>=32)). Y1T line L = d7*32 + l32.
#define BPITCH 226
__global__ __launch_bounds__(256) void k_rowfft0(const float2* __restrict__ P,
                                                 const float2* __restrict__ coil,
                                                 float2* __restrict__ Y1T,
                                                 const float2* __restrict__ twg,
                                                 int chunkStart) {
    __shared__ float2 buf[8][BPITCH];
    int tid = threadIdx.x;
    int lane = tid & 63, wv = tid >> 6, hi = lane >> 5, l32 = lane & 31;
    int h0 = blockIdx.x * 8, d = blockIdx.y, cz = blockIdx.z;
    int row = h0 + 2 * wv + hi;
    const float2* w32g = twg + TW_W32;
    const float2* w7g  = twg + TW_W7;
    const float2* b224 = twg + TW_B224;

    const float2* prow = P + (size_t)d * HWn + (size_t)row * Wn;
    const float2* crow = coil + (size_t)(chunkStart + cz) * HWn + (size_t)row * Wn;

    // load + coil-mul (coalesced, 2x256B segments per instruction)
    float2 xb[7];
#pragma unroll
    for (int b = 0; b < 7; ++b) xb[b] = cmul(prow[32 * b + l32], crow[32 * b + l32]);

    // DFT7: y[d7] = sum_b xb[b] * W7^{b*d7}
    float2 y[7];
#pragma unroll
    for (int d7 = 0; d7 < 7; ++d7) {
        float2 s = xb[0];
#pragma unroll
        for (int b = 1; b < 7; ++b) s = cfma(xb[b], w7g[(b * d7) % 7], s);
        y[d7] = s;
    }
    // twiddle W224^{l32*d7}
    float2 tp[7]; twpow(tp, b224[l32]);
#pragma unroll
    for (int d7 = 1; d7 < 7; ++d7) y[d7] = cmul(y[d7], tp[d7]);

    // FFT32 across each 32-lane half, DIF (bit-rev out; folded into line order)
#pragma unroll
    for (int s = 0; s < 5; ++s) {
        int dist = 16 >> s;
        float2 wst = w32g[(l32 & (dist - 1)) << s];
        bool hi2 = (l32 & dist) != 0;
#pragma unroll
        for (int d7 = 0; d7 < 7; ++d7) {
            float2 t = shflx2(y[d7], dist);
            float2 sum = cadd(y[d7], t);
            float2 dif = cmul(csub(t, y[d7]), wst);
            y[d7] = hi2 ? dif : sum;
        }
    }

    // deposit to LDS: row-local, line L = d7*32 + l32
#pragma unroll
    for (int d7 = 0; d7 < 7; ++d7) buf[2 * wv + hi][d7 * 32 + l32] = y[d7];
    __syncthreads();

    // store Y1T in 64B segments: 8 consecutive h per line
    float2* img = Y1T + ((size_t)cz * Dn + d) * (size_t)HWn;
#pragma unroll
    for (int i = tid; i < 8 * 224; i += 256) {
        int hh = i & 7, L = i >> 3;
        img[(size_t)L * Hn + h0 + hh] = buf[hh][L];
    }
}

// ---------- column FFT448 + mask + IFFT448, pure register lane-FFT (line-order agnostic) ----------
__global__ __launch_bounds__(256) void k_colfft(float2* __restrict__ Y1T,
                                                const float* __restrict__ maskP,
                                                const float2* __restrict__ twg) {
    __shared__ float2 tws[TW_N2];
    int tid = threadIdx.x;
    int lane = tid & 63, wv = tid >> 6;
    for (int i = tid; i < TW_N2; i += 256) tws[i] = twg[i];
    __syncthreads();

    const float2* w7t  = tws + TW_W7;
    const float2* w64t = tws + TW_W64;
    const float2* b448l = tws + TW_B448L;

    int L = blockIdx.x * 4 + wv;
    int d = blockIdx.y, cz = blockIdx.z;
    float2* line = Y1T + ((size_t)cz * Dn + d) * (size_t)HWn + (size_t)L * Hn;

    float2 xb[7];
#pragma unroll
    for (int b = 0; b < 7; ++b) xb[b] = line[64 * b + lane];

    // forward DFT7
    float2 y[7];
#pragma unroll
    for (int d7 = 0; d7 < 7; ++d7) {
        float2 s = xb[0];
#pragma unroll
        for (int b = 1; b < 7; ++b) s = cfma(xb[b], w7t[(b * d7) % 7], s);
        y[d7] = s;
    }
    float2 tp[7]; twpow(tp, b448l[lane]);
#pragma unroll
    for (int d7 = 1; d7 < 7; ++d7) y[d7] = cmul(y[d7], tp[d7]);

    // FFT64 across lanes, DIF
#pragma unroll
    for (int s = 0; s < 6; ++s) {
        int dist = 32 >> s;
        float2 wst = w64t[(lane & (dist - 1)) << s];
        bool hi = (lane & dist) != 0;
#pragma unroll
        for (int d7 = 0; d7 < 7; ++d7) {
            float2 t = shflx2(y[d7], dist);
            float2 sum = cadd(y[d7], t);
            float2 dif = cmul(csub(t, y[d7]), wst);
            y[d7] = hi ? dif : sum;
        }
    }

    // mask: lane holds H-freq index 7*brev6(lane)+d7
    int rb = (brev5(lane & 31) << 1) | (lane >> 5);
    const float* mrow = maskP + (size_t)L * Hn + 7 * rb;
#pragma unroll
    for (int d7 = 0; d7 < 7; ++d7) {
        float m = mrow[d7];
        y[d7].x *= m; y[d7].y *= m;
    }

    // inverse FFT64, DIT (bit-rev in, natural out)
#pragma unroll
    for (int s = 0; s < 6; ++s) {
        int dist = 1 << s;
        float2 wst = w64t[(lane & (dist - 1)) << (5 - s)];
        wst.y = -wst.y;
        bool hi = (lane & dist) != 0;
#pragma unroll
        for (int d7 = 0; d7 < 7; ++d7) {
            float2 t = shflx2(y[d7], dist);
            float2 uu = hi ? t : y[d7];
            float2 vv = hi ? y[d7] : t;
            float2 wtv = cmul(vv, wst);
            y[d7] = hi ? csub(uu, wtv) : cadd(uu, wtv);
        }
    }
#pragma unroll
    for (int d7 = 1; d7 < 7; ++d7) {
        float2 c = make_float2(tp[d7].x, -tp[d7].y);
        y[d7] = cmul(y[d7], c);
    }
#pragma unroll
    for (int b = 0; b < 7; ++b) {
        float2 s = y[0];
#pragma unroll
        for (int d7 = 1; d7 < 7; ++d7) {
            float2 wq = w7t[(b * d7) % 7]; wq.y = -wq.y;
            s = cfma(y[d7], wq, s);
        }
        xb[b] = s;
    }
#pragma unroll
    for (int b = 0; b < 7; ++b) line[64 * b + lane] = xb[b];
}

// ---------- fused inverse row FFT + conj-coil + coil-sum + q/dot epilogue ----------
// Block 256 = 4 waves, 8 rows; loops over cc coils, accumulating in registers.
__global__ __launch_bounds__(256) void k_irow_combine(const float2* __restrict__ Y1T,
                                                      const float2* __restrict__ coil,
                                                      const float2* __restrict__ P,
                                                      float2* __restrict__ Q,
                                                      const float* __restrict__ miu,
                                                      double* __restrict__ S,
                                                      const float2* __restrict__ twg,
                                                      int cc, int chunkStart,
                                                      int first, int last, int it) {
    __shared__ float2 buf[8][BPITCH];
    int tid = threadIdx.x;
    int lane = tid & 63, wv = tid >> 6, hi = lane >> 5, l32 = lane & 31;
    int h0 = blockIdx.x * 8, d = blockIdx.y;
    int row = h0 + 2 * wv + hi;
    const float2* w32g = twg + TW_W32;
    const float2* w7g  = twg + TW_W7;
    const float2* b224 = twg + TW_B224;

    float2 tp[7]; twpow(tp, b224[l32]);

    float2 acc[7];
#pragma unroll
    for (int b = 0; b < 7; ++b) acc[b] = make_float2(0.f, 0.f);

    for (int cz = 0; cz < cc; ++cz) {
        __syncthreads();   // protect buf from previous iteration's readers
        const float2* img = Y1T + ((size_t)cz * Dn + d) * (size_t)HWn;
#pragma unroll
        for (int i = tid; i < 8 * 224; i += 256) {
            int hh = i & 7, L = i >> 3;
            buf[hh][L] = img[(size_t)L * Hn + h0 + hh];
        }
        __syncthreads();

        // lane l32 reads line L = d7*32 + l32  -> holds m = brev5(l32) (DIT-ready)
        float2 y[7];
#pragma unroll
        for (int d7 = 0; d7 < 7; ++d7) y[d7] = buf[2 * wv + hi][d7 * 32 + l32];

        // inverse FFT32 across half-wave, DIT (bit-rev in, natural out), conj twiddles
#pragma unroll
        for (int s = 0; s < 5; ++s) {
            int dist = 1 << s;
            float2 wst = w32g[(l32 & (dist - 1)) << (4 - s)];
            wst.y = -wst.y;
            bool hi2 = (l32 & dist) != 0;
#pragma unroll
            for (int d7 = 0; d7 < 7; ++d7) {
                float2 t = shflx2(y[d7], dist);
                float2 uu = hi2 ? t : y[d7];
                float2 vv = hi2 ? y[d7] : t;
                float2 wtv = cmul(vv, wst);
                y[d7] = hi2 ? csub(uu, wtv) : cadd(uu, wtv);
            }
        }
        // conj twiddle W224^{-l32*d7}
#pragma unroll
        for (int d7 = 1; d7 < 7; ++d7) {
            float2 c = make_float2(tp[d7].x, -tp[d7].y);
            y[d7] = cmul(y[d7], c);
        }
        // inverse DFT7 + conj-coil accumulate
        const float2* crow = coil + (size_t)(chunkStart + cz) * HWn + (size_t)row * Wn;
#pragma unroll
        for (int b = 0; b < 7; ++b) {
            float2 s = y[0];
#pragma unroll
            for (int d7 = 1; d7 < 7; ++d7) {
                float2 wq = w7g[(b * d7) % 7]; wq.y = -wq.y;
                s = cfma(y[d7], wq, s);
            }
            float2 c = crow[32 * b + l32];
            acc[b].x += fmaf(s.x, c.x, s.y * c.y);
            acc[b].y += fmaf(s.y, c.x, -s.x * c.y);
        }
    }

    // epilogue: q = mu*p + acc (or q += acc), dots on last chunk
    float mu = fabsf(miu[0]);
    const float2* prow = P + (size_t)d * HWn + (size_t)row * Wn;
    float2* qrow = Q + (size_t)d * HWn + (size_t)row * Wn;
    double ar = 0.0, ai = 0.0;
#pragma unroll
    for (int b = 0; b < 7; ++b) {
        float2 pv = prow[32 * b + l32];
        float2 s0;
        if (first) s0 = make_float2(fmaf(mu, pv.x, acc[b].x), fmaf(mu, pv.y, acc[b].y));
        else { float2 qv = qrow[32 * b + l32]; s0 = cadd(qv, acc[b]); }
        qrow[32 * b + l32] = s0;
        if (last) {
            ar += (double)(s0.x * pv.x + s0.y * pv.y);
            ai += (double)(s0.y * pv.x - s0.x * pv.y);
        }
    }
    if (last) {
        ar = waveReduce(ar);
        ai = waveReduce(ai);
        if ((threadIdx.x & 63) == 0) {
            atomicAdd(&S[8 + it], ar);
            atomicAdd(&S[16 + it], ai);
        }
    }
}

// ---------- CG scalar updates ----------
__global__ void k_update_br(const double* __restrict__ Sin, double* __restrict__ S, int it,
                            const float2* __restrict__ p, const float2* __restrict__ q,
                            float2* __restrict__ b, float2* __restrict__ r) {
    double rr = Sin[it], qr = Sin[8 + it], qi = Sin[16 + it];
    double den = qr * qr + qi * qi;
    float arf = (float)(rr * qr / den);
    float aif = (float)(-rr * qi / den);
    double acc = 0.0;
    for (int e = blockIdx.x * blockDim.x + threadIdx.x; e < DHWn; e += gridDim.x * blockDim.x) {
        float2 pv = p[e], qv = q[e], bv = b[e], rv = r[e];
        bv.x += arf * pv.x - aif * pv.y;
        bv.y += arf * pv.y + aif * pv.x;
        b[e] = bv;
        rv.x -= arf * qv.x - aif * qv.y;
        rv.y -= arf * qv.y + aif * qv.x;
        r[e] = rv;
        acc += (double)rv.x * rv.x + (double)rv.y * rv.y;
    }
    acc = waveReduce(acc);
    if ((threadIdx.x & 63) == 0) atomicAdd(&S[it + 1], acc);
}

__global__ void k_update_p(const double* __restrict__ S, int it,
                           const float2* __restrict__ r, float2* __restrict__ p) {
    float beta = (float)(S[it + 1] / S[it]);
    for (int e = blockIdx.x * blockDim.x + threadIdx.x; e < DHWn; e += gridDim.x * blockDim.x) {
        float2 rv = r[e], pv = p[e];
        p[e] = make_float2(fmaf(beta, pv.x, rv.x), fmaf(beta, pv.y, rv.y));
    }
}

__global__ void k_output(const float2* __restrict__ b, float* __restrict__ out) {
    for (int e = blockIdx.x * blockDim.x + threadIdx.x; e < DHWn; e += gridDim.x * blockDim.x) {
        int d = e / HWn, rem = e - d * HWn;
        int h = rem / Wn, w = rem - h * Wn;
        int hs = h + Hn / 2; if (hs >= Hn) hs -= Hn;
        int ws = w + Wn / 2; if (ws >= Wn) ws -= Wn;
        float2 v = b[d * HWn + hs * Wn + ws];
        out[e] = v.x;
        out[DHWn + e] = v.y;
    }
}

extern "C" void kernel_launch(void* const* d_in, const int* in_sizes, int n_in,
                              void* d_out, int out_size, void* d_ws, size_t ws_size,
                              hipStream_t stream) {
    const float* z      = (const float*)d_in[0];
    const float* zf     = (const float*)d_in[1];
    const float* coil_r = (const float*)d_in[2];
    const float* coil_i = (const float*)d_in[3];
    const int*   maskp  = (const int*)d_in[4];
    const float* miu    = (const float*)d_in[5];
    float* out = (float*)d_out;

    char* w = (char*)d_ws;
    size_t off = 0;
    auto carve = [&](size_t bytes) -> void* {
        void* ptr = w + off;
        off += (bytes + 511) & ~(size_t)511;
        return ptr;
    };
    float2* P     = (float2*)carve((size_t)DHWn * 8);
    float2* R     = (float2*)carve((size_t)DHWn * 8);
    float2* Bv    = (float2*)carve((size_t)DHWn * 8);
    float2* Q     = (float2*)carve((size_t)DHWn * 8);
    float2* COIL  = (float2*)carve((size_t)Cn * HWn * 8);
    float*  MASKP = (float*)carve((size_t)HWn * 4);
    float2* TWS   = (float2*)carve(TW_N2 * 8);
    double* S     = (double*)carve(64 * 8);

    size_t imgSet = (size_t)DHWn * 8;   // one coil-slot (12 slices)
    int cc = 1;
    {
        const int opts[4] = {10, 5, 2, 1};
        for (int i = 0; i < 4; ++i) {
            if (off + (size_t)opts[i] * imgSet <= ws_size) { cc = opts[i]; break; }
        }
    }
    float2* Y1T = (float2*)carve((size_t)cc * imgSet);   // staged lines [c][d][L][h]
    int nch = Cn / cc;

    k_init_misc<<<1, 256, 0, stream>>>(TWS, S);
    k_build_p<<<1024, 256, 0, stream>>>(z, zf, miu, P, R, Bv, S);
    k_build_coil<<<1024, 256, 0, stream>>>(coil_r, coil_i, COIL);
    k_build_mask<<<512, 256, 0, stream>>>(maskp, MASKP);

    for (int it = 0; it < 5; ++it) {
        for (int ch = 0; ch < nch; ++ch) {
            int cs = ch * cc;
            dim3 gf(Hn / 8, Dn, cc);   // 56 x 12 x cc, 256-thr (4 waves, 8 rows)
            dim3 gc(Wn / 4, Dn, cc);   // 56 x 12 x cc, 256-thr (4 indep waves)
            dim3 gi(Hn / 8, Dn);       // 56 x 12, loops over cc coils
            k_rowfft0<<<gf, 256, 0, stream>>>(P, COIL, Y1T, TWS, cs);
            k_colfft<<<gc, 256, 0, stream>>>(Y1T, MASKP, TWS);
            k_irow_combine<<<gi, 256, 0, stream>>>(Y1T, COIL, P, Q, miu, S, TWS,
                                                   cc, cs, ch == 0 ? 1 : 0,
                                                   ch == nch - 1 ? 1 : 0, it);
        }
        k_update_br<<<1024, 256, 0, stream>>>(S, S, it, P, Q, Bv, R);
        if (it < 4) k_update_p<<<1024, 256, 0, stream>>>(S, it, R, P);
    }
    k_output<<<1024, 256, 0, stream>>>(Bv, out);
}